// Round 7
// baseline (742.795 us; speedup 1.0000x reference)
//
#include <hip/hip_runtime.h>
#include <math.h>
#include <float.h>

#define NN 50000
#define EE 800000
#define FF 64
#define EDIM 16
#define GG 64
#define NB64 782   // ceil(NN/64)

typedef short bf16x8 __attribute__((ext_vector_type(8)));
typedef float f32x4 __attribute__((ext_vector_type(4)));

__device__ inline unsigned short bf_rne(float v) {
  unsigned int u = __float_as_uint(v);
  unsigned int r = (u + 0x7FFFu + ((u >> 16) & 1u)) >> 16;
  return (unsigned short)r;
}
__device__ inline float bf_up(unsigned short h) {
  return __uint_as_float(((unsigned int)h) << 16);
}
__device__ inline void split4(float4 v, ushort4& h, ushort4& l) {
  h.x = bf_rne(v.x); h.y = bf_rne(v.y); h.z = bf_rne(v.z); h.w = bf_rne(v.w);
  l.x = bf_rne(v.x - bf_up(h.x));
  l.y = bf_rne(v.y - bf_up(h.y));
  l.z = bf_rne(v.z - bf_up(h.z));
  l.w = bf_rne(v.w - bf_up(h.w));
}
__device__ inline float dot16(float4 a, float4 b, float4 c, float4 d, const float* mw) {
  return a.x * mw[0] + a.y * mw[1] + a.z * mw[2] + a.w * mw[3]
       + b.x * mw[4] + b.y * mw[5] + b.z * mw[6] + b.w * mw[7]
       + c.x * mw[8] + c.y * mw[9] + c.z * mw[10] + c.w * mw[11]
       + d.x * mw[12] + d.y * mw[13] + d.z * mw[14] + d.w * mw[15];
}

// ---------------------------------------------------------------- degree
__global__ void k_deg(const int* __restrict__ eidx, int* __restrict__ deg) {
  int e = blockIdx.x * 256 + threadIdx.x;
  if (e < EE) atomicAdd(&deg[eidx[EE + e]], 1);
}

// ---------------------------------------------------------------- avg log(deg+1)
__global__ void k_avglog(const int* __restrict__ deg, double* __restrict__ acc) {
  int n = blockIdx.x * 256 + threadIdx.x;
  float v = (n < NN) ? logf((float)deg[n] + 1.0f) : 0.0f;
  __shared__ float s[256];
  s[threadIdx.x] = v;
  __syncthreads();
  for (int o = 128; o > 0; o >>= 1) {
    if (threadIdx.x < o) s[threadIdx.x] += s[threadIdx.x + o];
    __syncthreads();
  }
  if (threadIdx.x == 0) atomicAdd(acc, (double)s[0]);
}

// ---------------------------------------------------------------- exclusive scan of deg -> offsets (single block)
__global__ __launch_bounds__(1024) void k_scan(const int* __restrict__ deg, int* __restrict__ offsets) {
  __shared__ int wsum[16];
  __shared__ int s_carry;
  int t = threadIdx.x;
  int lane = t & 63;
  int wid = t >> 6;
  if (t == 0) s_carry = 0;
  __syncthreads();
  for (int base = 0; base < NN; base += 1024) {
    int idx = base + t;
    int v = (idx < NN) ? deg[idx] : 0;
    int x = v;
    #pragma unroll
    for (int o = 1; o < 64; o <<= 1) {
      int y = __shfl_up(x, o);
      if (lane >= o) x += y;
    }
    if (lane == 63) wsum[wid] = x;
    __syncthreads();
    if (wid == 0 && lane < 16) {
      int wv = wsum[lane];
      #pragma unroll
      for (int o = 1; o < 16; o <<= 1) {
        int y = __shfl_up(wv, o);
        if (lane >= o) wv += y;
      }
      wsum[lane] = wv;
    }
    __syncthreads();
    int pre = (wid > 0 ? wsum[wid - 1] : 0) + s_carry;
    if (idx < NN) offsets[idx] = pre + x - v;  // exclusive
    __syncthreads();
    if (t == 0) s_carry += wsum[15];
    __syncthreads();
  }
  if (threadIdx.x == 0) offsets[NN] = s_carry;
}

// ---------------------------------------------------------------- scatter edges into CSR slots
__global__ void k_scatter(const int* __restrict__ eidx, const int* __restrict__ offsets,
                          int* __restrict__ cursor, int2* __restrict__ pack) {
  int e = blockIdx.x * 256 + threadIdx.x;
  if (e < EE) {
    int s = eidx[e];
    int d = eidx[EE + e];
    int pos = offsets[d] + atomicAdd(&cursor[d], 1);
    pack[pos] = make_int2(s, e);
  }
}

// ---------------------------------------------------------------- amp/att
__global__ void k_ampatt(const int* __restrict__ deg, const double* __restrict__ acc,
                         float* __restrict__ amp, float* __restrict__ att) {
  int n = blockIdx.x * 256 + threadIdx.x;
  if (n < NN) {
    float avg = (float)(acc[0] / (double)NN);
    float d = (float)deg[n];
    float logd = logf(fmaxf(d, 1.0f) + 1.0f);
    amp[n] = logd / avg;
    att[n] = avg / logd;
  }
}

// ---------------------------------------------------------------- per-layer prep
__global__ __launch_bounds__(256) void k_prep2(const float* __restrict__ We, const float* __restrict__ be,
                                               const float* __restrict__ Wpre, const float* __restrict__ bpre,
                                               const float* __restrict__ Wpost, const float* __restrict__ bpost,
                                               const float* __restrict__ Wlin, const float* __restrict__ blin,
                                               float* __restrict__ Mw, float* __restrict__ bconst,
                                               unsigned short* __restrict__ WcT_h, unsigned short* __restrict__ WcT_l,
                                               unsigned short* __restrict__ WxT_h, unsigned short* __restrict__ WxT_l,
                                               float* __restrict__ bcomb) {
  int id = blockIdx.x * 256 + threadIdx.x;
  if (id < 53248) {                      // WcombT
    int k = id >> 6, f = id & 63;
    float a = 0.0f;
    for (int j = 0; j < FF; j++) a += Wpost[(size_t)k * FF + j] * Wlin[j * FF + f];
    unsigned short h = bf_rne(a);
    WcT_h[f * 832 + k] = h;
    WcT_l[f * 832 + k] = bf_rne(a - bf_up(h));
  } else if (id < 61440) {               // WxT
    int lid = id - 53248;
    int j = lid >> 6, k = lid & 63;
    float v = (j < 64) ? Wpre[k * FF + j] : Wpre[(64 + k) * FF + (j - 64)];
    unsigned short h = bf_rne(v);
    WxT_h[j * 64 + k] = h;
    WxT_l[j * 64 + k] = bf_rne(v - bf_up(h));
  } else if (id < 62464) {               // Mw
    int lid = id - 61440;
    int k = lid >> 6, f = lid & 63;
    float a = 0.0f;
    for (int j = 0; j < FF; j++) a += We[k * FF + j] * Wpre[(128 + j) * FF + f];
    Mw[k * FF + f] = a;
  } else {                               // biases
    int f = threadIdx.x;
    if (blockIdx.x == 244 && f < 64) {
      float b = bpre[f];
      for (int j = 0; j < FF; j++) b += be[j] * Wpre[(128 + j) * FF + f];
      bconst[f] = b;
      float c = blin[f];
      for (int j = 0; j < FF; j++) c += bpost[j] * Wlin[j * FF + f];
      bcomb[f] = c;
    }
  }
}

// ---------------------------------------------------------------- [Xd|Xs] = x @ Wx  via bf16x3 MFMA
__global__ __launch_bounds__(256) void k_xform(const float* __restrict__ x,
                                               const unsigned short* __restrict__ WxT_h,
                                               const unsigned short* __restrict__ WxT_l,
                                               float* __restrict__ Xd, float* __restrict__ Xs) {
  __shared__ unsigned short Ah[64 * 72], Al[64 * 72];
  __shared__ unsigned short Bh[128 * 72], Bl[128 * 72];
  int t = threadIdx.x;
  int n0 = blockIdx.x * 64;
  // stage B (weights, [col][k] layout, row stride 72); each thread: 32 k-elems
  {
    int j = t >> 1, half = t & 1;
    const ushort4* srch = (const ushort4*)(WxT_h + j * 64 + half * 32);
    const ushort4* srcl = (const ushort4*)(WxT_l + j * 64 + half * 32);
    #pragma unroll
    for (int i = 0; i < 8; i++) {
      *(ushort4*)&Bh[j * 72 + half * 32 + i * 4] = srch[i];
      *(ushort4*)&Bl[j * 72 + half * 32 + i * 4] = srcl[i];
    }
  }
  // stage A (x rows, f32 -> hi/lo bf16)
  {
    int r = t >> 2, c0 = (t & 3) * 16;
    int n = n0 + r;
    bool rok = n < NN;
    const float4* src = (const float4*)(x + (size_t)n * FF + c0);
    #pragma unroll
    for (int c4 = 0; c4 < 4; c4++) {
      float4 v = rok ? src[c4] : make_float4(0.f, 0.f, 0.f, 0.f);
      ushort4 h4, l4;
      split4(v, h4, l4);
      *(ushort4*)&Ah[r * 72 + c0 + c4 * 4] = h4;
      *(ushort4*)&Al[r * 72 + c0 + c4 * 4] = l4;
    }
  }
  __syncthreads();
  int lane = t & 63;
  int l15 = lane & 15;
  int quad = lane >> 4;
  int w = __builtin_amdgcn_readfirstlane(t >> 6);
  int rbase = (w & 1) * 32;
  int cbase = (w >> 1) * 64;
  f32x4 acc[2][4];
  #pragma unroll
  for (int rt = 0; rt < 2; rt++)
    #pragma unroll
    for (int ct = 0; ct < 4; ct++) acc[rt][ct] = (f32x4){0.f, 0.f, 0.f, 0.f};

  #pragma unroll
  for (int ks = 0; ks < 2; ks++) {
    bf16x8 a_h[2], a_l[2];
    #pragma unroll
    for (int rt = 0; rt < 2; rt++) {
      int row = rbase + rt * 16 + l15;
      a_h[rt] = *(const bf16x8*)&Ah[row * 72 + ks * 32 + quad * 8];
      a_l[rt] = *(const bf16x8*)&Al[row * 72 + ks * 32 + quad * 8];
    }
    #pragma unroll
    for (int ct = 0; ct < 4; ct++) {
      int col = cbase + ct * 16 + l15;
      bf16x8 b_h = *(const bf16x8*)&Bh[col * 72 + ks * 32 + quad * 8];
      bf16x8 b_l = *(const bf16x8*)&Bl[col * 72 + ks * 32 + quad * 8];
      #pragma unroll
      for (int rt = 0; rt < 2; rt++) {
        acc[rt][ct] = __builtin_amdgcn_mfma_f32_16x16x32_bf16(a_h[rt], b_h, acc[rt][ct], 0, 0, 0);
        acc[rt][ct] = __builtin_amdgcn_mfma_f32_16x16x32_bf16(a_h[rt], b_l, acc[rt][ct], 0, 0, 0);
        acc[rt][ct] = __builtin_amdgcn_mfma_f32_16x16x32_bf16(a_l[rt], b_h, acc[rt][ct], 0, 0, 0);
      }
    }
  }
  // store: cols 0..63 -> Xd, 64..127 -> Xs
  #pragma unroll
  for (int rt = 0; rt < 2; rt++) {
    #pragma unroll
    for (int ct = 0; ct < 4; ct++) {
      int col = cbase + ct * 16 + l15;
      float* dst = (col < 64) ? (Xd + col) : (Xs + col - 64);
      #pragma unroll
      for (int reg = 0; reg < 4; reg++) {
        int n = n0 + rbase + rt * 16 + quad * 4 + reg;
        if (n < NN) dst[(size_t)n * FF] = acc[rt][ct][reg];
      }
    }
  }
}

// ---------------------------------------------------------------- per-node CSR aggregation, 2 waves per node
// wave-batched pack load + shfl broadcast; partials combined via LDS
__global__ __launch_bounds__(256) void k_agg(const int2* __restrict__ pack, const int* __restrict__ offsets,
                                             const int* __restrict__ deg, const float* __restrict__ eattr,
                                             const float* __restrict__ Mw, const float* __restrict__ bconst,
                                             const float* __restrict__ Xd, const float* __restrict__ Xs,
                                             float* __restrict__ aggs) {
  __shared__ float shs[4][64], shq[4][64], shmn[4][64], shmx[4][64];
  int t = threadIdx.x;
  int wid = t >> 6;        // 0..3
  int lane = t & 63;
  int local = wid >> 1;    // node slot in block
  int half = wid & 1;
  int n = blockIdx.x * 2 + local;
  bool ok = n < NN;
  float mw[16];
  #pragma unroll
  for (int k = 0; k < 16; k++) mw[k] = Mw[k * FF + lane];
  float base_h = 0.f;
  int b0 = 0, b1 = 0;
  if (ok) {
    base_h = Xd[(size_t)n * FF + lane] + bconst[lane];
    int o0 = offsets[n], o1 = offsets[n + 1];
    int mid = o0 + ((o1 - o0) >> 1);
    b0 = half ? mid : o0;
    b1 = half ? o1 : mid;
  }
  float s = 0.f, sq = 0.f, mn = FLT_MAX, mx = -FLT_MAX;
  for (int base = b0; base < b1; base += 64) {
    int m = min(64, b1 - base);
    int2 pv = make_int2(0, 0);
    if (base + lane < b1) pv = pack[base + lane];
    for (int j = 0; j < m; j++) {
      int src = __shfl(pv.x, j), eid = __shfl(pv.y, j);
      float xs = Xs[(size_t)src * FF + lane];
      const float4* p = (const float4*)(eattr + (size_t)eid * EDIM);
      float4 a0 = p[0], a1 = p[1], a2 = p[2], a3 = p[3];
      float h = base_h + xs + dot16(a0, a1, a2, a3, mw);
      s += h;
      sq += h * h;
      mn = fminf(mn, h);
      mx = fmaxf(mx, h);
    }
  }
  shs[wid][lane] = s;
  shq[wid][lane] = sq;
  shmn[wid][lane] = mn;
  shmx[wid][lane] = mx;
  __syncthreads();
  if (half == 0 && ok) {
    float S = s + shs[wid + 1][lane];
    float Q = sq + shq[wid + 1][lane];
    float MN = fminf(mn, shmn[wid + 1][lane]);
    float MX = fmaxf(mx, shmx[wid + 1][lane]);
    float d = (float)deg[n];
    float dc = fmaxf(d, 1.0f);
    float mean = S / dc;
    float msq = Q / dc;
    float sd = sqrtf(fmaxf(msq - mean * mean, 0.0f) + 1e-5f);
    bool has = d > 0.0f;
    float vmn = has ? MN : 0.0f;
    float vmx = has ? MX : 0.0f;
    size_t b = (size_t)n * 256;
    aggs[b + lane] = mean;
    aggs[b + 64 + lane] = vmn;
    aggs[b + 128 + lane] = vmx;
    aggs[b + 192 + lane] = sd;
  }
}

// ---------------------------------------------------------------- y = A @ Wcomb + bcomb  (bf16x3 MFMA) + BN partials
__global__ __launch_bounds__(256) void k_post(const float* __restrict__ x, const float* __restrict__ aggs,
                                              const float* __restrict__ amp, const float* __restrict__ att,
                                              const unsigned short* __restrict__ WcT_h,
                                              const unsigned short* __restrict__ WcT_l,
                                              const float* __restrict__ bcomb,
                                              float* __restrict__ y, float* __restrict__ partials) {
  __shared__ unsigned short Ah[64 * 72], Al[64 * 72];
  __shared__ unsigned short Bh[64 * 72], Bl[64 * 72];
  __shared__ float red_s[4][32], red_q[4][32];
  int t = threadIdx.x;
  int n0 = blockIdx.x * 64;
  int lane = t & 63;
  int l15 = lane & 15;
  int quad = lane >> 4;
  int w = __builtin_amdgcn_readfirstlane(t >> 6);
  int rbase = (w & 1) * 32;
  int cbase = (w >> 1) * 32;

  int ar = t >> 2;                // staging row (A) / col (B)
  int ac0 = (t & 3) * 16;
  int an = n0 + ar;
  bool rok = an < NN;
  float sc_amp = rok ? amp[an] : 0.f;
  float sc_att = rok ? att[an] : 0.f;
  const float* xrow = x + (size_t)an * FF;
  const float* arow = aggs + (size_t)an * 256;

  f32x4 acc[2][2];
  #pragma unroll
  for (int rt = 0; rt < 2; rt++)
    #pragma unroll
    for (int ct = 0; ct < 2; ct++) acc[rt][ct] = (f32x4){0.f, 0.f, 0.f, 0.f};

  for (int kc = 0; kc < 13; kc++) {
    // ---- stage A chunk [64 rows][64 k]
    const float* srcb;
    float scale = 1.0f;
    if (kc == 0) {
      srcb = xrow;
    } else {
      int kcm = kc - 1;
      srcb = arow + (kcm & 3) * 64;
      int sel = kcm >> 2;
      scale = (sel == 0) ? 1.0f : (sel == 1 ? sc_amp : sc_att);
    }
    #pragma unroll
    for (int c4 = 0; c4 < 4; c4++) {
      float4 v = rok ? *(const float4*)(srcb + ac0 + c4 * 4) : make_float4(0.f, 0.f, 0.f, 0.f);
      v.x *= scale; v.y *= scale; v.z *= scale; v.w *= scale;
      ushort4 h4, l4;
      split4(v, h4, l4);
      *(ushort4*)&Ah[ar * 72 + ac0 + c4 * 4] = h4;
      *(ushort4*)&Al[ar * 72 + ac0 + c4 * 4] = l4;
    }
    // ---- stage B chunk [64 cols][64 k]; each thread: 16 k-elems
    {
      int kbase = kc * 64;
      const ushort4* sh = (const ushort4*)(WcT_h + ar * 832 + kbase + ac0);
      const ushort4* sl = (const ushort4*)(WcT_l + ar * 832 + kbase + ac0);
      #pragma unroll
      for (int i = 0; i < 4; i++) {
        *(ushort4*)&Bh[ar * 72 + ac0 + i * 4] = sh[i];
        *(ushort4*)&Bl[ar * 72 + ac0 + i * 4] = sl[i];
      }
    }
    __syncthreads();
    #pragma unroll
    for (int ks = 0; ks < 2; ks++) {
      bf16x8 a_h[2], a_l[2], b_h[2], b_l[2];
      #pragma unroll
      for (int rt = 0; rt < 2; rt++) {
        int row = rbase + rt * 16 + l15;
        a_h[rt] = *(const bf16x8*)&Ah[row * 72 + ks * 32 + quad * 8];
        a_l[rt] = *(const bf16x8*)&Al[row * 72 + ks * 32 + quad * 8];
      }
      #pragma unroll
      for (int ct = 0; ct < 2; ct++) {
        int col = cbase + ct * 16 + l15;
        b_h[ct] = *(const bf16x8*)&Bh[col * 72 + ks * 32 + quad * 8];
        b_l[ct] = *(const bf16x8*)&Bl[col * 72 + ks * 32 + quad * 8];
      }
      #pragma unroll
      for (int rt = 0; rt < 2; rt++)
        #pragma unroll
        for (int ct = 0; ct < 2; ct++) {
          acc[rt][ct] = __builtin_amdgcn_mfma_f32_16x16x32_bf16(a_h[rt], b_h[ct], acc[rt][ct], 0, 0, 0);
          acc[rt][ct] = __builtin_amdgcn_mfma_f32_16x16x32_bf16(a_h[rt], b_l[ct], acc[rt][ct], 0, 0, 0);
          acc[rt][ct] = __builtin_amdgcn_mfma_f32_16x16x32_bf16(a_l[rt], b_h[ct], acc[rt][ct], 0, 0, 0);
        }
    }
    __syncthreads();
  }

  // ---- epilogue: bias, store y, BN partials
  float ps[2] = {0.f, 0.f}, pq[2] = {0.f, 0.f};
  #pragma unroll
  for (int ct = 0; ct < 2; ct++) {
    int col = cbase + ct * 16 + l15;
    float bc = bcomb[col];
    #pragma unroll
    for (int rt = 0; rt < 2; rt++) {
      #pragma unroll
      for (int reg = 0; reg < 4; reg++) {
        int n = n0 + rbase + rt * 16 + quad * 4 + reg;
        float v = acc[rt][ct][reg] + bc;
        if (n < NN) {
          y[(size_t)n * FF + col] = v;
          ps[ct] += v;
          pq[ct] += v * v;
        }
      }
    }
  }
  #pragma unroll
  for (int ct = 0; ct < 2; ct++) {
    ps[ct] += __shfl_xor(ps[ct], 16);
    ps[ct] += __shfl_xor(ps[ct], 32);
    pq[ct] += __shfl_xor(pq[ct], 16);
    pq[ct] += __shfl_xor(pq[ct], 32);
  }
  if (quad == 0) {
    #pragma unroll
    for (int ct = 0; ct < 2; ct++) {
      red_s[w][ct * 16 + l15] = ps[ct];
      red_q[w][ct * 16 + l15] = pq[ct];
    }
  }
  __syncthreads();
  if (t < 64) {
    float ss, qq;
    if (t < 32) { ss = red_s[0][t] + red_s[1][t]; qq = red_q[0][t] + red_q[1][t]; }
    else        { ss = red_s[2][t - 32] + red_s[3][t - 32]; qq = red_q[2][t - 32] + red_q[3][t - 32]; }
    partials[(size_t)blockIdx.x * 128 + t] = ss;
    partials[(size_t)blockIdx.x * 128 + 64 + t] = qq;
  }
}

// ---------------------------------------------------------------- reduce BN partials -> scb (scale, offset)
__global__ __launch_bounds__(1024) void k_bnfin(const float* __restrict__ partials,
                                                const float* __restrict__ gamma, const float* __restrict__ beta,
                                                float* __restrict__ scb) {
  __shared__ float red[1024];
  __shared__ double tot[128];
  int t = threadIdx.x;
  int c = t & 127, seg = t >> 7;
  float s = 0.f;
  for (int i = seg; i < NB64; i += 8) s += partials[(size_t)i * 128 + c];
  red[t] = s;
  __syncthreads();
  if (t < 128) {
    double d = 0.0;
    #pragma unroll
    for (int sg = 0; sg < 8; sg++) d += (double)red[sg * 128 + t];
    tot[t] = d;
  }
  __syncthreads();
  if (t < 64) {
    double mu = tot[t] / (double)NN;
    double var = tot[64 + t] / (double)NN - mu * mu;
    float sc = gamma[t] * rsqrtf((float)fmax(var, 0.0) + 1e-5f);
    scb[t] = sc;
    scb[64 + t] = beta[t] - (float)mu * sc;
  }
}

// ---------------------------------------------------------------- BN apply + relu, elementwise float4
__global__ __launch_bounds__(256) void k_bnapply(const float* __restrict__ y, const float* __restrict__ scb,
                                                 float* __restrict__ xout) {
  int idx = blockIdx.x * 256 + threadIdx.x;  // over NN*16 float4s
  if (idx >= NN * 16) return;
  int f4 = idx & 15;
  float4 v = ((const float4*)y)[idx];
  float4 sc = ((const float4*)scb)[f4];
  float4 of = ((const float4*)(scb + 64))[f4];
  v.x = fmaxf(v.x * sc.x + of.x, 0.0f);
  v.y = fmaxf(v.y * sc.y + of.y, 0.0f);
  v.z = fmaxf(v.z * sc.z + of.z, 0.0f);
  v.w = fmaxf(v.w * sc.w + of.w, 0.0f);
  ((float4*)xout)[idx] = v;
}

// ---------------------------------------------------------------- pooling over sorted batch
__global__ __launch_bounds__(256) void k_pool(const float* __restrict__ x, const int* __restrict__ batch,
                                              float* __restrict__ psum, float* __restrict__ cnt) {
  int lane = threadIdx.x & 63;
  int wv = threadIdx.x >> 6;
  int wglobal = blockIdx.x * 4 + wv;
  int nw = gridDim.x * 4;
  int per = (NN + nw - 1) / nw;
  int n0 = wglobal * per;
  int n1 = min(n0 + per, NN);
  if (n0 >= n1) return;
  int gcur = batch[n0];
  float acc = 0.0f;
  int count = 0;
  for (int n = n0; n < n1; n++) {
    int g = batch[n];
    float v = x[(size_t)n * FF + lane];
    if (g != gcur) {
      atomicAdd(&psum[gcur * FF + lane], acc);
      if (lane == 0) atomicAdd(&cnt[gcur], (float)count);
      gcur = g; acc = 0.0f; count = 0;
    }
    acc += v;
    count++;
  }
  atomicAdd(&psum[gcur * FF + lane], acc);
  if (lane == 0) atomicAdd(&cnt[gcur], (float)count);
}

// ---------------------------------------------------------------- final MLP over pooled means
__global__ void k_final(const float* __restrict__ psum, const float* __restrict__ cnt,
                        const float* __restrict__ W1, const float* __restrict__ b1,
                        const float* __restrict__ W2, const float* __restrict__ b2, float* __restrict__ out) {
  int g = threadIdx.x;
  if (g >= GG) return;
  float c = fmaxf(cnt[g], 1.0f);
  float gm[64];
  #pragma unroll
  for (int i = 0; i < 64; i++) gm[i] = psum[g * FF + i] / c;
  float o = b2[0];
  for (int h = 0; h < 40; h++) {
    float a = b1[h];
    #pragma unroll
    for (int i = 0; i < 64; i++) a += gm[i] * W1[i * 40 + h];
    o += fmaxf(a, 0.0f) * W2[h];
  }
  out[g] = o;
}

// ================================================================ launch
extern "C" void kernel_launch(void* const* d_in, const int* in_sizes, int n_in,
                              void* d_out, int out_size, void* d_ws, size_t ws_size,
                              hipStream_t stream) {
  (void)in_sizes; (void)n_in; (void)out_size; (void)ws_size;
  const float* x0    = (const float*)d_in[0];
  const float* eattr = (const float*)d_in[1];
  const float* We    = (const float*)d_in[2];
  const float* be    = (const float*)d_in[3];
  const float* Wpre  = (const float*)d_in[4];
  const float* bpre  = (const float*)d_in[5];
  const float* Wpost = (const float*)d_in[6];
  const float* bpost = (const float*)d_in[7];
  const float* Wlin  = (const float*)d_in[8];
  const float* blin  = (const float*)d_in[9];
  const float* gamma = (const float*)d_in[10];
  const float* beta  = (const float*)d_in[11];
  const float* W1    = (const float*)d_in[12];
  const float* b1    = (const float*)d_in[13];
  const float* W2    = (const float*)d_in[14];
  const float* b2    = (const float*)d_in[15];
  const int* eidx    = (const int*)d_in[16];
  const int* batch   = (const int*)d_in[17];
  float* out = (float*)d_out;

  char* w = (char*)d_ws;
  size_t off = 0;
  auto alloc = [&](size_t bytes) -> void* {
    void* p = w + off;
    off += bytes;
    off = (off + 255) & ~(size_t)255;
    return p;
  };
  int*    deg     = (int*)alloc(NN * sizeof(int));
  int*    offsets = (int*)alloc((NN + 1) * sizeof(int));
  int*    cursor  = (int*)alloc(NN * sizeof(int));
  int2*   pack    = (int2*)alloc(EE * sizeof(int2));
  double* avgacc  = (double*)alloc(sizeof(double));
  float*  amp     = (float*)alloc(NN * sizeof(float));
  float*  att     = (float*)alloc(NN * sizeof(float));
  float*  Mw      = (float*)alloc(EDIM * FF * sizeof(float));
  float*  bconst  = (float*)alloc(FF * sizeof(float));
  float*  bcomb   = (float*)alloc(FF * sizeof(float));
  float*  scb     = (float*)alloc(2 * FF * sizeof(float));
  unsigned short* WcT_h = (unsigned short*)alloc(FF * 832 * sizeof(unsigned short));
  unsigned short* WcT_l = (unsigned short*)alloc(FF * 832 * sizeof(unsigned short));
  unsigned short* WxT_h = (unsigned short*)alloc(128 * 64 * sizeof(unsigned short));
  unsigned short* WxT_l = (unsigned short*)alloc(128 * 64 * sizeof(unsigned short));
  float*  partials = (float*)alloc((size_t)NB64 * 128 * sizeof(float));
  float*  Xd      = (float*)alloc((size_t)NN * FF * sizeof(float));
  float*  Xs      = (float*)alloc((size_t)NN * FF * sizeof(float));
  float*  aggs    = (float*)alloc((size_t)NN * 256 * sizeof(float));
  float*  ybuf    = (float*)alloc((size_t)NN * FF * sizeof(float));
  float*  xcur    = (float*)alloc((size_t)NN * FF * sizeof(float));
  float*  psum    = (float*)alloc((GG * FF + GG) * sizeof(float));
  float*  cnt     = psum + GG * FF;

  hipMemsetAsync(deg, 0, NN * sizeof(int), stream);
  hipMemsetAsync(cursor, 0, NN * sizeof(int), stream);
  hipMemsetAsync(avgacc, 0, sizeof(double), stream);
  hipMemsetAsync(psum, 0, (GG * FF + GG) * sizeof(float), stream);

  k_deg<<<(EE + 255) / 256, 256, 0, stream>>>(eidx, deg);
  k_avglog<<<(NN + 255) / 256, 256, 0, stream>>>(deg, avgacc);
  k_scan<<<1, 1024, 0, stream>>>(deg, offsets);
  k_scatter<<<(EE + 255) / 256, 256, 0, stream>>>(eidx, offsets, cursor, pack);
  k_ampatt<<<(NN + 255) / 256, 256, 0, stream>>>(deg, avgacc, amp, att);

  const float* xin = x0;
  for (int l = 0; l < 2; l++) {
    k_prep2<<<245, 256, 0, stream>>>(We + l * EDIM * FF, be + l * FF, Wpre + (size_t)l * 3 * FF * FF,
                                     bpre + l * FF, Wpost + (size_t)l * 832 * FF, bpost + l * FF,
                                     Wlin + l * FF * FF, blin + l * FF,
                                     Mw, bconst, WcT_h, WcT_l, WxT_h, WxT_l, bcomb);
    k_xform<<<NB64, 256, 0, stream>>>(xin, WxT_h, WxT_l, Xd, Xs);
    k_agg<<<(NN + 1) / 2, 256, 0, stream>>>(pack, offsets, deg, eattr, Mw, bconst, Xd, Xs, aggs);
    k_post<<<NB64, 256, 0, stream>>>(xin, aggs, amp, att, WcT_h, WcT_l, bcomb, ybuf, partials);
    k_bnfin<<<1, 1024, 0, stream>>>(partials, gamma + l * FF, beta + l * FF, scb);
    k_bnapply<<<(NN * 16 + 255) / 256, 256, 0, stream>>>(ybuf, scb, xcur);
    xin = xcur;
  }
  k_pool<<<200, 256, 0, stream>>>(xcur, batch, psum, cnt);
  k_final<<<1, 64, 0, stream>>>(psum, cnt, W1, b1, W2, b2, out);
}

// Round 8
// 738.601 us; speedup vs baseline: 1.0057x; 1.0057x over previous
//
#include <hip/hip_runtime.h>
#include <math.h>
#include <float.h>

#define NN 50000
#define EE 800000
#define FF 64
#define EDIM 16
#define GG 64
#define NB64 782   // ceil(NN/64)
#define NPB 16     // nodes per k_agg block

typedef short bf16x8 __attribute__((ext_vector_type(8)));
typedef float f32x4 __attribute__((ext_vector_type(4)));

__device__ inline unsigned short bf_rne(float v) {
  unsigned int u = __float_as_uint(v);
  unsigned int r = (u + 0x7FFFu + ((u >> 16) & 1u)) >> 16;
  return (unsigned short)r;
}
__device__ inline float bf_up(unsigned short h) {
  return __uint_as_float(((unsigned int)h) << 16);
}
__device__ inline void split4(float4 v, ushort4& h, ushort4& l) {
  h.x = bf_rne(v.x); h.y = bf_rne(v.y); h.z = bf_rne(v.z); h.w = bf_rne(v.w);
  l.x = bf_rne(v.x - bf_up(h.x));
  l.y = bf_rne(v.y - bf_up(h.y));
  l.z = bf_rne(v.z - bf_up(h.z));
  l.w = bf_rne(v.w - bf_up(h.w));
}
__device__ inline float dot16(float4 a, float4 b, float4 c, float4 d, const float* mw) {
  return a.x * mw[0] + a.y * mw[1] + a.z * mw[2] + a.w * mw[3]
       + b.x * mw[4] + b.y * mw[5] + b.z * mw[6] + b.w * mw[7]
       + c.x * mw[8] + c.y * mw[9] + c.z * mw[10] + c.w * mw[11]
       + d.x * mw[12] + d.y * mw[13] + d.z * mw[14] + d.w * mw[15];
}

// ---------------------------------------------------------------- degree
__global__ void k_deg(const int* __restrict__ eidx, int* __restrict__ deg) {
  int e = blockIdx.x * 256 + threadIdx.x;
  if (e < EE) atomicAdd(&deg[eidx[EE + e]], 1);
}

// ---------------------------------------------------------------- avg log(deg+1)
__global__ void k_avglog(const int* __restrict__ deg, double* __restrict__ acc) {
  int n = blockIdx.x * 256 + threadIdx.x;
  float v = (n < NN) ? logf((float)deg[n] + 1.0f) : 0.0f;
  __shared__ float s[256];
  s[threadIdx.x] = v;
  __syncthreads();
  for (int o = 128; o > 0; o >>= 1) {
    if (threadIdx.x < o) s[threadIdx.x] += s[threadIdx.x + o];
    __syncthreads();
  }
  if (threadIdx.x == 0) atomicAdd(acc, (double)s[0]);
}

// ---------------------------------------------------------------- exclusive scan of deg -> offsets (single block)
__global__ __launch_bounds__(1024) void k_scan(const int* __restrict__ deg, int* __restrict__ offsets) {
  __shared__ int wsum[16];
  __shared__ int s_carry;
  int t = threadIdx.x;
  int lane = t & 63;
  int wid = t >> 6;
  if (t == 0) s_carry = 0;
  __syncthreads();
  for (int base = 0; base < NN; base += 1024) {
    int idx = base + t;
    int v = (idx < NN) ? deg[idx] : 0;
    int x = v;
    #pragma unroll
    for (int o = 1; o < 64; o <<= 1) {
      int y = __shfl_up(x, o);
      if (lane >= o) x += y;
    }
    if (lane == 63) wsum[wid] = x;
    __syncthreads();
    if (wid == 0 && lane < 16) {
      int wv = wsum[lane];
      #pragma unroll
      for (int o = 1; o < 16; o <<= 1) {
        int y = __shfl_up(wv, o);
        if (lane >= o) wv += y;
      }
      wsum[lane] = wv;
    }
    __syncthreads();
    int pre = (wid > 0 ? wsum[wid - 1] : 0) + s_carry;
    if (idx < NN) offsets[idx] = pre + x - v;  // exclusive
    __syncthreads();
    if (t == 0) s_carry += wsum[15];
    __syncthreads();
  }
  if (threadIdx.x == 0) offsets[NN] = s_carry;
}

// ---------------------------------------------------------------- scatter edges into CSR slots
__global__ void k_scatter(const int* __restrict__ eidx, const int* __restrict__ offsets,
                          int* __restrict__ cursor, int2* __restrict__ pack) {
  int e = blockIdx.x * 256 + threadIdx.x;
  if (e < EE) {
    int s = eidx[e];
    int d = eidx[EE + e];
    int pos = offsets[d] + atomicAdd(&cursor[d], 1);
    pack[pos] = make_int2(s, e);
  }
}

// ---------------------------------------------------------------- amp/att
__global__ void k_ampatt(const int* __restrict__ deg, const double* __restrict__ acc,
                         float* __restrict__ amp, float* __restrict__ att) {
  int n = blockIdx.x * 256 + threadIdx.x;
  if (n < NN) {
    float avg = (float)(acc[0] / (double)NN);
    float d = (float)deg[n];
    float logd = logf(fmaxf(d, 1.0f) + 1.0f);
    amp[n] = logd / avg;
    att[n] = avg / logd;
  }
}

// ---------------------------------------------------------------- per-layer prep
__global__ __launch_bounds__(256) void k_prep2(const float* __restrict__ We, const float* __restrict__ be,
                                               const float* __restrict__ Wpre, const float* __restrict__ bpre,
                                               const float* __restrict__ Wpost, const float* __restrict__ bpost,
                                               const float* __restrict__ Wlin, const float* __restrict__ blin,
                                               float* __restrict__ Mw, float* __restrict__ bconst,
                                               unsigned short* __restrict__ WcT_h, unsigned short* __restrict__ WcT_l,
                                               unsigned short* __restrict__ WxT_h, unsigned short* __restrict__ WxT_l,
                                               float* __restrict__ bcomb) {
  int id = blockIdx.x * 256 + threadIdx.x;
  if (id < 53248) {                      // WcombT
    int k = id >> 6, f = id & 63;
    float a = 0.0f;
    for (int j = 0; j < FF; j++) a += Wpost[(size_t)k * FF + j] * Wlin[j * FF + f];
    unsigned short h = bf_rne(a);
    WcT_h[f * 832 + k] = h;
    WcT_l[f * 832 + k] = bf_rne(a - bf_up(h));
  } else if (id < 61440) {               // WxT
    int lid = id - 53248;
    int j = lid >> 6, k = lid & 63;
    float v = (j < 64) ? Wpre[k * FF + j] : Wpre[(64 + k) * FF + (j - 64)];
    unsigned short h = bf_rne(v);
    WxT_h[j * 64 + k] = h;
    WxT_l[j * 64 + k] = bf_rne(v - bf_up(h));
  } else if (id < 62464) {               // Mw
    int lid = id - 61440;
    int k = lid >> 6, f = lid & 63;
    float a = 0.0f;
    for (int j = 0; j < FF; j++) a += We[k * FF + j] * Wpre[(128 + j) * FF + f];
    Mw[k * FF + f] = a;
  } else {                               // biases
    int f = threadIdx.x;
    if (blockIdx.x == 244 && f < 64) {
      float b = bpre[f];
      for (int j = 0; j < FF; j++) b += be[j] * Wpre[(128 + j) * FF + f];
      bconst[f] = b;
      float c = blin[f];
      for (int j = 0; j < FF; j++) c += bpost[j] * Wlin[j * FF + f];
      bcomb[f] = c;
    }
  }
}

// ---------------------------------------------------------------- [Xd|Xs] = x @ Wx  via bf16x3 MFMA
__global__ __launch_bounds__(256) void k_xform(const float* __restrict__ x,
                                               const unsigned short* __restrict__ WxT_h,
                                               const unsigned short* __restrict__ WxT_l,
                                               float* __restrict__ Xd, float* __restrict__ Xs) {
  __shared__ unsigned short Ah[64 * 72], Al[64 * 72];
  __shared__ unsigned short Bh[128 * 72], Bl[128 * 72];
  int t = threadIdx.x;
  int n0 = blockIdx.x * 64;
  // stage B (weights, [col][k] layout, row stride 72); each thread: 32 k-elems
  {
    int j = t >> 1, half = t & 1;
    const ushort4* srch = (const ushort4*)(WxT_h + j * 64 + half * 32);
    const ushort4* srcl = (const ushort4*)(WxT_l + j * 64 + half * 32);
    #pragma unroll
    for (int i = 0; i < 8; i++) {
      *(ushort4*)&Bh[j * 72 + half * 32 + i * 4] = srch[i];
      *(ushort4*)&Bl[j * 72 + half * 32 + i * 4] = srcl[i];
    }
  }
  // stage A (x rows, f32 -> hi/lo bf16)
  {
    int r = t >> 2, c0 = (t & 3) * 16;
    int n = n0 + r;
    bool rok = n < NN;
    const float4* src = (const float4*)(x + (size_t)n * FF + c0);
    #pragma unroll
    for (int c4 = 0; c4 < 4; c4++) {
      float4 v = rok ? src[c4] : make_float4(0.f, 0.f, 0.f, 0.f);
      ushort4 h4, l4;
      split4(v, h4, l4);
      *(ushort4*)&Ah[r * 72 + c0 + c4 * 4] = h4;
      *(ushort4*)&Al[r * 72 + c0 + c4 * 4] = l4;
    }
  }
  __syncthreads();
  int lane = t & 63;
  int l15 = lane & 15;
  int quad = lane >> 4;
  int w = __builtin_amdgcn_readfirstlane(t >> 6);
  int rbase = (w & 1) * 32;
  int cbase = (w >> 1) * 64;
  f32x4 acc[2][4];
  #pragma unroll
  for (int rt = 0; rt < 2; rt++)
    #pragma unroll
    for (int ct = 0; ct < 4; ct++) acc[rt][ct] = (f32x4){0.f, 0.f, 0.f, 0.f};

  #pragma unroll
  for (int ks = 0; ks < 2; ks++) {
    bf16x8 a_h[2], a_l[2];
    #pragma unroll
    for (int rt = 0; rt < 2; rt++) {
      int row = rbase + rt * 16 + l15;
      a_h[rt] = *(const bf16x8*)&Ah[row * 72 + ks * 32 + quad * 8];
      a_l[rt] = *(const bf16x8*)&Al[row * 72 + ks * 32 + quad * 8];
    }
    #pragma unroll
    for (int ct = 0; ct < 4; ct++) {
      int col = cbase + ct * 16 + l15;
      bf16x8 b_h = *(const bf16x8*)&Bh[col * 72 + ks * 32 + quad * 8];
      bf16x8 b_l = *(const bf16x8*)&Bl[col * 72 + ks * 32 + quad * 8];
      #pragma unroll
      for (int rt = 0; rt < 2; rt++) {
        acc[rt][ct] = __builtin_amdgcn_mfma_f32_16x16x32_bf16(a_h[rt], b_h, acc[rt][ct], 0, 0, 0);
        acc[rt][ct] = __builtin_amdgcn_mfma_f32_16x16x32_bf16(a_h[rt], b_l, acc[rt][ct], 0, 0, 0);
        acc[rt][ct] = __builtin_amdgcn_mfma_f32_16x16x32_bf16(a_l[rt], b_h, acc[rt][ct], 0, 0, 0);
      }
    }
  }
  // store: cols 0..63 -> Xd, 64..127 -> Xs
  #pragma unroll
  for (int rt = 0; rt < 2; rt++) {
    #pragma unroll
    for (int ct = 0; ct < 4; ct++) {
      int col = cbase + ct * 16 + l15;
      float* dst = (col < 64) ? (Xd + col) : (Xs + col - 64);
      #pragma unroll
      for (int reg = 0; reg < 4; reg++) {
        int n = n0 + rbase + rt * 16 + quad * 4 + reg;
        if (n < NN) dst[(size_t)n * FF] = acc[rt][ct][reg];
      }
    }
  }
}

// ---------------------------------------------------------------- per-node CSR aggregation: block-cooperative LDS staging
// 16 nodes/block; stage 64-edge chunks (Xs rows + eattr rows) into LDS with
// massively parallel independent loads, then reduce from LDS (index-derived
// addresses, fully pipelined). Kills the serial dependent-gather chain.
__global__ __launch_bounds__(256) void k_agg(const int2* __restrict__ pack, const int* __restrict__ offsets,
                                             const float* __restrict__ eattr,
                                             const float* __restrict__ Mw, const float* __restrict__ bconst,
                                             const float* __restrict__ Xd, const float* __restrict__ Xs,
                                             float* __restrict__ aggs) {
  __shared__ float XsS[64 * 68];   // row stride 68 words (16B-aligned, conflict-light)
  __shared__ float EaS[64 * 20];   // row stride 20 words
  __shared__ int offS[NPB + 1];
  int t = threadIdx.x;
  int lane = t & 63;
  int w = t >> 6;
  int nb0 = blockIdx.x * NPB;
  if (t <= NPB) offS[t] = offsets[min(nb0 + t, NN)];
  __syncthreads();
  int E0 = offS[0], E1 = offS[NPB];
  float mw[16];
  #pragma unroll
  for (int k = 0; k < 16; k++) mw[k] = Mw[k * FF + lane];
  float bc = bconst[lane];
  int no0[4], no1[4];
  float bh[4], s[4], sq[4], mn[4], mx[4];
  #pragma unroll
  for (int nd = 0; nd < 4; nd++) {
    int n = nb0 + w * 4 + nd;
    no0[nd] = offS[w * 4 + nd];
    no1[nd] = offS[w * 4 + nd + 1];
    bh[nd] = (n < NN) ? Xd[(size_t)n * FF + lane] + bc : 0.f;
    s[nd] = 0.f; sq[nd] = 0.f; mn[nd] = FLT_MAX; mx[nd] = -FLT_MAX;
  }
  for (int cb = E0; cb < E1; cb += 64) {
    int ce = min(cb + 64, E1);
    // ---- stage: 256 threads, 4 per edge row; all loads independent
    {
      int el = t >> 2;
      int c0 = (t & 3) * 16;
      int e = cb + el;
      if (e < ce) {
        int2 pe = pack[e];
        const float4* sp = (const float4*)(Xs + (size_t)pe.x * FF + c0);
        float4 v0 = sp[0], v1 = sp[1], v2 = sp[2], v3 = sp[3];
        float4* dp = (float4*)&XsS[el * 68 + c0];
        dp[0] = v0; dp[1] = v1; dp[2] = v2; dp[3] = v3;
        if ((t & 3) == 0) {
          const float4* ep = (const float4*)(eattr + (size_t)pe.y * EDIM);
          float4 q0 = ep[0], q1 = ep[1], q2 = ep[2], q3 = ep[3];
          float4* dq = (float4*)&EaS[el * 20];
          dq[0] = q0; dq[1] = q1; dq[2] = q2; dq[3] = q3;
        }
      }
    }
    __syncthreads();
    // ---- reduce from LDS
    #pragma unroll
    for (int nd = 0; nd < 4; nd++) {
      int a0 = max(no0[nd], cb), a1 = min(no1[nd], ce);
      for (int e = a0; e < a1; e++) {
        int el = e - cb;
        float xs = XsS[el * 68 + lane];
        const float4* q = (const float4*)&EaS[el * 20];
        float4 q0 = q[0], q1 = q[1], q2 = q[2], q3 = q[3];
        float h = bh[nd] + xs + dot16(q0, q1, q2, q3, mw);
        s[nd] += h;
        sq[nd] += h * h;
        mn[nd] = fminf(mn[nd], h);
        mx[nd] = fmaxf(mx[nd], h);
      }
    }
    __syncthreads();
  }
  #pragma unroll
  for (int nd = 0; nd < 4; nd++) {
    int n = nb0 + w * 4 + nd;
    if (n < NN) {
      float d = (float)(no1[nd] - no0[nd]);
      float dc = fmaxf(d, 1.0f);
      float mean = s[nd] / dc;
      float msq = sq[nd] / dc;
      float sd = sqrtf(fmaxf(msq - mean * mean, 0.0f) + 1e-5f);
      bool has = d > 0.0f;
      float vmn = has ? mn[nd] : 0.0f;
      float vmx = has ? mx[nd] : 0.0f;
      size_t b = (size_t)n * 256;
      aggs[b + lane] = mean;
      aggs[b + 64 + lane] = vmn;
      aggs[b + 128 + lane] = vmx;
      aggs[b + 192 + lane] = sd;
    }
  }
}

// ---------------------------------------------------------------- y = A @ Wcomb + bcomb  (bf16x3 MFMA) + BN partials
__global__ __launch_bounds__(256) void k_post(const float* __restrict__ x, const float* __restrict__ aggs,
                                              const float* __restrict__ amp, const float* __restrict__ att,
                                              const unsigned short* __restrict__ WcT_h,
                                              const unsigned short* __restrict__ WcT_l,
                                              const float* __restrict__ bcomb,
                                              float* __restrict__ y, float* __restrict__ partials) {
  __shared__ unsigned short Ah[64 * 72], Al[64 * 72];
  __shared__ unsigned short Bh[64 * 72], Bl[64 * 72];
  __shared__ float red_s[4][32], red_q[4][32];
  int t = threadIdx.x;
  int n0 = blockIdx.x * 64;
  int lane = t & 63;
  int l15 = lane & 15;
  int quad = lane >> 4;
  int w = __builtin_amdgcn_readfirstlane(t >> 6);
  int rbase = (w & 1) * 32;
  int cbase = (w >> 1) * 32;

  int ar = t >> 2;                // staging row (A) / col (B)
  int ac0 = (t & 3) * 16;
  int an = n0 + ar;
  bool rok = an < NN;
  float sc_amp = rok ? amp[an] : 0.f;
  float sc_att = rok ? att[an] : 0.f;
  const float* xrow = x + (size_t)an * FF;
  const float* arow = aggs + (size_t)an * 256;

  f32x4 acc[2][2];
  #pragma unroll
  for (int rt = 0; rt < 2; rt++)
    #pragma unroll
    for (int ct = 0; ct < 2; ct++) acc[rt][ct] = (f32x4){0.f, 0.f, 0.f, 0.f};

  for (int kc = 0; kc < 13; kc++) {
    // ---- stage A chunk [64 rows][64 k]
    const float* srcb;
    float scale = 1.0f;
    if (kc == 0) {
      srcb = xrow;
    } else {
      int kcm = kc - 1;
      srcb = arow + (kcm & 3) * 64;
      int sel = kcm >> 2;
      scale = (sel == 0) ? 1.0f : (sel == 1 ? sc_amp : sc_att);
    }
    #pragma unroll
    for (int c4 = 0; c4 < 4; c4++) {
      float4 v = rok ? *(const float4*)(srcb + ac0 + c4 * 4) : make_float4(0.f, 0.f, 0.f, 0.f);
      v.x *= scale; v.y *= scale; v.z *= scale; v.w *= scale;
      ushort4 h4, l4;
      split4(v, h4, l4);
      *(ushort4*)&Ah[ar * 72 + ac0 + c4 * 4] = h4;
      *(ushort4*)&Al[ar * 72 + ac0 + c4 * 4] = l4;
    }
    // ---- stage B chunk [64 cols][64 k]; each thread: 16 k-elems
    {
      int kbase = kc * 64;
      const ushort4* sh = (const ushort4*)(WcT_h + ar * 832 + kbase + ac0);
      const ushort4* sl = (const ushort4*)(WcT_l + ar * 832 + kbase + ac0);
      #pragma unroll
      for (int i = 0; i < 4; i++) {
        *(ushort4*)&Bh[ar * 72 + ac0 + i * 4] = sh[i];
        *(ushort4*)&Bl[ar * 72 + ac0 + i * 4] = sl[i];
      }
    }
    __syncthreads();
    #pragma unroll
    for (int ks = 0; ks < 2; ks++) {
      bf16x8 a_h[2], a_l[2], b_h[2], b_l[2];
      #pragma unroll
      for (int rt = 0; rt < 2; rt++) {
        int row = rbase + rt * 16 + l15;
        a_h[rt] = *(const bf16x8*)&Ah[row * 72 + ks * 32 + quad * 8];
        a_l[rt] = *(const bf16x8*)&Al[row * 72 + ks * 32 + quad * 8];
      }
      #pragma unroll
      for (int ct = 0; ct < 2; ct++) {
        int col = cbase + ct * 16 + l15;
        b_h[ct] = *(const bf16x8*)&Bh[col * 72 + ks * 32 + quad * 8];
        b_l[ct] = *(const bf16x8*)&Bl[col * 72 + ks * 32 + quad * 8];
      }
      #pragma unroll
      for (int rt = 0; rt < 2; rt++)
        #pragma unroll
        for (int ct = 0; ct < 2; ct++) {
          acc[rt][ct] = __builtin_amdgcn_mfma_f32_16x16x32_bf16(a_h[rt], b_h[ct], acc[rt][ct], 0, 0, 0);
          acc[rt][ct] = __builtin_amdgcn_mfma_f32_16x16x32_bf16(a_h[rt], b_l[ct], acc[rt][ct], 0, 0, 0);
          acc[rt][ct] = __builtin_amdgcn_mfma_f32_16x16x32_bf16(a_l[rt], b_h[ct], acc[rt][ct], 0, 0, 0);
        }
    }
    __syncthreads();
  }

  // ---- epilogue: bias, store y, BN partials
  float ps[2] = {0.f, 0.f}, pq[2] = {0.f, 0.f};
  #pragma unroll
  for (int ct = 0; ct < 2; ct++) {
    int col = cbase + ct * 16 + l15;
    float bc = bcomb[col];
    #pragma unroll
    for (int rt = 0; rt < 2; rt++) {
      #pragma unroll
      for (int reg = 0; reg < 4; reg++) {
        int n = n0 + rbase + rt * 16 + quad * 4 + reg;
        float v = acc[rt][ct][reg] + bc;
        if (n < NN) {
          y[(size_t)n * FF + col] = v;
          ps[ct] += v;
          pq[ct] += v * v;
        }
      }
    }
  }
  #pragma unroll
  for (int ct = 0; ct < 2; ct++) {
    ps[ct] += __shfl_xor(ps[ct], 16);
    ps[ct] += __shfl_xor(ps[ct], 32);
    pq[ct] += __shfl_xor(pq[ct], 16);
    pq[ct] += __shfl_xor(pq[ct], 32);
  }
  if (quad == 0) {
    #pragma unroll
    for (int ct = 0; ct < 2; ct++) {
      red_s[w][ct * 16 + l15] = ps[ct];
      red_q[w][ct * 16 + l15] = pq[ct];
    }
  }
  __syncthreads();
  if (t < 64) {
    float ss, qq;
    if (t < 32) { ss = red_s[0][t] + red_s[1][t]; qq = red_q[0][t] + red_q[1][t]; }
    else        { ss = red_s[2][t - 32] + red_s[3][t - 32]; qq = red_q[2][t - 32] + red_q[3][t - 32]; }
    partials[(size_t)blockIdx.x * 128 + t] = ss;
    partials[(size_t)blockIdx.x * 128 + 64 + t] = qq;
  }
}

// ---------------------------------------------------------------- reduce BN partials -> scb (scale, offset)
__global__ __launch_bounds__(1024) void k_bnfin(const float* __restrict__ partials,
                                                const float* __restrict__ gamma, const float* __restrict__ beta,
                                                float* __restrict__ scb) {
  __shared__ float red[1024];
  __shared__ double tot[128];
  int t = threadIdx.x;
  int c = t & 127, seg = t >> 7;
  float s = 0.f;
  for (int i = seg; i < NB64; i += 8) s += partials[(size_t)i * 128 + c];
  red[t] = s;
  __syncthreads();
  if (t < 128) {
    double d = 0.0;
    #pragma unroll
    for (int sg = 0; sg < 8; sg++) d += (double)red[sg * 128 + t];
    tot[t] = d;
  }
  __syncthreads();
  if (t < 64) {
    double mu = tot[t] / (double)NN;
    double var = tot[64 + t] / (double)NN - mu * mu;
    float sc = gamma[t] * rsqrtf((float)fmax(var, 0.0) + 1e-5f);
    scb[t] = sc;
    scb[64 + t] = beta[t] - (float)mu * sc;
  }
}

// ---------------------------------------------------------------- BN apply + relu, elementwise float4
__global__ __launch_bounds__(256) void k_bnapply(const float* __restrict__ y, const float* __restrict__ scb,
                                                 float* __restrict__ xout) {
  int idx = blockIdx.x * 256 + threadIdx.x;  // over NN*16 float4s
  if (idx >= NN * 16) return;
  int f4 = idx & 15;
  float4 v = ((const float4*)y)[idx];
  float4 sc = ((const float4*)scb)[f4];
  float4 of = ((const float4*)(scb + 64))[f4];
  v.x = fmaxf(v.x * sc.x + of.x, 0.0f);
  v.y = fmaxf(v.y * sc.y + of.y, 0.0f);
  v.z = fmaxf(v.z * sc.z + of.z, 0.0f);
  v.w = fmaxf(v.w * sc.w + of.w, 0.0f);
  ((float4*)xout)[idx] = v;
}

// ---------------------------------------------------------------- pooling over sorted batch
__global__ __launch_bounds__(256) void k_pool(const float* __restrict__ x, const int* __restrict__ batch,
                                              float* __restrict__ psum, float* __restrict__ cnt) {
  int lane = threadIdx.x & 63;
  int wv = threadIdx.x >> 6;
  int wglobal = blockIdx.x * 4 + wv;
  int nw = gridDim.x * 4;
  int per = (NN + nw - 1) / nw;
  int n0 = wglobal * per;
  int n1 = min(n0 + per, NN);
  if (n0 >= n1) return;
  int gcur = batch[n0];
  float acc = 0.0f;
  int count = 0;
  for (int n = n0; n < n1; n++) {
    int g = batch[n];
    float v = x[(size_t)n * FF + lane];
    if (g != gcur) {
      atomicAdd(&psum[gcur * FF + lane], acc);
      if (lane == 0) atomicAdd(&cnt[gcur], (float)count);
      gcur = g; acc = 0.0f; count = 0;
    }
    acc += v;
    count++;
  }
  atomicAdd(&psum[gcur * FF + lane], acc);
  if (lane == 0) atomicAdd(&cnt[gcur], (float)count);
}

// ---------------------------------------------------------------- final MLP over pooled means
__global__ void k_final(const float* __restrict__ psum, const float* __restrict__ cnt,
                        const float* __restrict__ W1, const float* __restrict__ b1,
                        const float* __restrict__ W2, const float* __restrict__ b2, float* __restrict__ out) {
  int g = threadIdx.x;
  if (g >= GG) return;
  float c = fmaxf(cnt[g], 1.0f);
  float gm[64];
  #pragma unroll
  for (int i = 0; i < 64; i++) gm[i] = psum[g * FF + i] / c;
  float o = b2[0];
  for (int h = 0; h < 40; h++) {
    float a = b1[h];
    #pragma unroll
    for (int i = 0; i < 64; i++) a += gm[i] * W1[i * 40 + h];
    o += fmaxf(a, 0.0f) * W2[h];
  }
  out[g] = o;
}

// ================================================================ launch
extern "C" void kernel_launch(void* const* d_in, const int* in_sizes, int n_in,
                              void* d_out, int out_size, void* d_ws, size_t ws_size,
                              hipStream_t stream) {
  (void)in_sizes; (void)n_in; (void)out_size; (void)ws_size;
  const float* x0    = (const float*)d_in[0];
  const float* eattr = (const float*)d_in[1];
  const float* We    = (const float*)d_in[2];
  const float* be    = (const float*)d_in[3];
  const float* Wpre  = (const float*)d_in[4];
  const float* bpre  = (const float*)d_in[5];
  const float* Wpost = (const float*)d_in[6];
  const float* bpost = (const float*)d_in[7];
  const float* Wlin  = (const float*)d_in[8];
  const float* blin  = (const float*)d_in[9];
  const float* gamma = (const float*)d_in[10];
  const float* beta  = (const float*)d_in[11];
  const float* W1    = (const float*)d_in[12];
  const float* b1    = (const float*)d_in[13];
  const float* W2    = (const float*)d_in[14];
  const float* b2    = (const float*)d_in[15];
  const int* eidx    = (const int*)d_in[16];
  const int* batch   = (const int*)d_in[17];
  float* out = (float*)d_out;

  char* w = (char*)d_ws;
  size_t off = 0;
  auto alloc = [&](size_t bytes) -> void* {
    void* p = w + off;
    off += bytes;
    off = (off + 255) & ~(size_t)255;
    return p;
  };
  int*    deg     = (int*)alloc(NN * sizeof(int));
  int*    offsets = (int*)alloc((NN + 1) * sizeof(int));
  int*    cursor  = (int*)alloc(NN * sizeof(int));
  int2*   pack    = (int2*)alloc(EE * sizeof(int2));
  double* avgacc  = (double*)alloc(sizeof(double));
  float*  amp     = (float*)alloc(NN * sizeof(float));
  float*  att     = (float*)alloc(NN * sizeof(float));
  float*  Mw      = (float*)alloc(EDIM * FF * sizeof(float));
  float*  bconst  = (float*)alloc(FF * sizeof(float));
  float*  bcomb   = (float*)alloc(FF * sizeof(float));
  float*  scb     = (float*)alloc(2 * FF * sizeof(float));
  unsigned short* WcT_h = (unsigned short*)alloc(FF * 832 * sizeof(unsigned short));
  unsigned short* WcT_l = (unsigned short*)alloc(FF * 832 * sizeof(unsigned short));
  unsigned short* WxT_h = (unsigned short*)alloc(128 * 64 * sizeof(unsigned short));
  unsigned short* WxT_l = (unsigned short*)alloc(128 * 64 * sizeof(unsigned short));
  float*  partials = (float*)alloc((size_t)NB64 * 128 * sizeof(float));
  float*  Xd      = (float*)alloc((size_t)NN * FF * sizeof(float));
  float*  Xs      = (float*)alloc((size_t)NN * FF * sizeof(float));
  float*  aggs    = (float*)alloc((size_t)NN * 256 * sizeof(float));
  float*  ybuf    = (float*)alloc((size_t)NN * FF * sizeof(float));
  float*  xcur    = (float*)alloc((size_t)NN * FF * sizeof(float));
  float*  psum    = (float*)alloc((GG * FF + GG) * sizeof(float));
  float*  cnt     = psum + GG * FF;

  hipMemsetAsync(deg, 0, NN * sizeof(int), stream);
  hipMemsetAsync(cursor, 0, NN * sizeof(int), stream);
  hipMemsetAsync(avgacc, 0, sizeof(double), stream);
  hipMemsetAsync(psum, 0, (GG * FF + GG) * sizeof(float), stream);

  k_deg<<<(EE + 255) / 256, 256, 0, stream>>>(eidx, deg);
  k_avglog<<<(NN + 255) / 256, 256, 0, stream>>>(deg, avgacc);
  k_scan<<<1, 1024, 0, stream>>>(deg, offsets);
  k_scatter<<<(EE + 255) / 256, 256, 0, stream>>>(eidx, offsets, cursor, pack);
  k_ampatt<<<(NN + 255) / 256, 256, 0, stream>>>(deg, avgacc, amp, att);

  const float* xin = x0;
  for (int l = 0; l < 2; l++) {
    k_prep2<<<245, 256, 0, stream>>>(We + l * EDIM * FF, be + l * FF, Wpre + (size_t)l * 3 * FF * FF,
                                     bpre + l * FF, Wpost + (size_t)l * 832 * FF, bpost + l * FF,
                                     Wlin + l * FF * FF, blin + l * FF,
                                     Mw, bconst, WcT_h, WcT_l, WxT_h, WxT_l, bcomb);
    k_xform<<<NB64, 256, 0, stream>>>(xin, WxT_h, WxT_l, Xd, Xs);
    k_agg<<<(NN + NPB - 1) / NPB, 256, 0, stream>>>(pack, offsets, eattr, Mw, bconst, Xd, Xs, aggs);
    k_post<<<NB64, 256, 0, stream>>>(xin, aggs, amp, att, WcT_h, WcT_l, bcomb, ybuf, partials);
    k_bnfin<<<1, 1024, 0, stream>>>(partials, gamma + l * FF, beta + l * FF, scb);
    k_bnapply<<<(NN * 16 + 255) / 256, 256, 0, stream>>>(ybuf, scb, xcur);
    xin = xcur;
  }
  k_pool<<<200, 256, 0, stream>>>(xcur, batch, psum, cnt);
  k_final<<<1, 64, 0, stream>>>(psum, cnt, W1, b1, W2, b2, out);
}

// Round 9
// 640.182 us; speedup vs baseline: 1.1603x; 1.1537x over previous
//
#include <hip/hip_runtime.h>
#include <math.h>
#include <float.h>

#define NN 50000
#define EE 800000
#define FF 64
#define EDIM 16
#define GG 64
#define NB64 782   // ceil(NN/64)

typedef short bf16x8 __attribute__((ext_vector_type(8)));
typedef float f32x4 __attribute__((ext_vector_type(4)));

__device__ inline unsigned short bf_rne(float v) {
  unsigned int u = __float_as_uint(v);
  unsigned int r = (u + 0x7FFFu + ((u >> 16) & 1u)) >> 16;
  return (unsigned short)r;
}
__device__ inline float bf_up(unsigned short h) {
  return __uint_as_float(((unsigned int)h) << 16);
}
__device__ inline void split4(float4 v, ushort4& h, ushort4& l) {
  h.x = bf_rne(v.x); h.y = bf_rne(v.y); h.z = bf_rne(v.z); h.w = bf_rne(v.w);
  l.x = bf_rne(v.x - bf_up(h.x));
  l.y = bf_rne(v.y - bf_up(h.y));
  l.z = bf_rne(v.z - bf_up(h.z));
  l.w = bf_rne(v.w - bf_up(h.w));
}
__device__ inline float blo(unsigned int u) { return __uint_as_float(u << 16); }
__device__ inline float bhi(unsigned int u) { return __uint_as_float(u & 0xFFFF0000u); }

// ---------------------------------------------------------------- degree
__global__ void k_deg(const int* __restrict__ eidx, int* __restrict__ deg) {
  int e = blockIdx.x * 256 + threadIdx.x;
  if (e < EE) atomicAdd(&deg[eidx[EE + e]], 1);
}

// ---------------------------------------------------------------- avg log(deg+1)
__global__ void k_avglog(const int* __restrict__ deg, double* __restrict__ acc) {
  int n = blockIdx.x * 256 + threadIdx.x;
  float v = (n < NN) ? logf((float)deg[n] + 1.0f) : 0.0f;
  __shared__ float s[256];
  s[threadIdx.x] = v;
  __syncthreads();
  for (int o = 128; o > 0; o >>= 1) {
    if (threadIdx.x < o) s[threadIdx.x] += s[threadIdx.x + o];
    __syncthreads();
  }
  if (threadIdx.x == 0) atomicAdd(acc, (double)s[0]);
}

// ---------------------------------------------------------------- exclusive scan of deg -> offsets (single block)
__global__ __launch_bounds__(1024) void k_scan(const int* __restrict__ deg, int* __restrict__ offsets) {
  __shared__ int wsum[16];
  __shared__ int s_carry;
  int t = threadIdx.x;
  int lane = t & 63;
  int wid = t >> 6;
  if (t == 0) s_carry = 0;
  __syncthreads();
  for (int base = 0; base < NN; base += 1024) {
    int idx = base + t;
    int v = (idx < NN) ? deg[idx] : 0;
    int x = v;
    #pragma unroll
    for (int o = 1; o < 64; o <<= 1) {
      int y = __shfl_up(x, o);
      if (lane >= o) x += y;
    }
    if (lane == 63) wsum[wid] = x;
    __syncthreads();
    if (wid == 0 && lane < 16) {
      int wv = wsum[lane];
      #pragma unroll
      for (int o = 1; o < 16; o <<= 1) {
        int y = __shfl_up(wv, o);
        if (lane >= o) wv += y;
      }
      wsum[lane] = wv;
    }
    __syncthreads();
    int pre = (wid > 0 ? wsum[wid - 1] : 0) + s_carry;
    if (idx < NN) offsets[idx] = pre + x - v;  // exclusive
    __syncthreads();
    if (t == 0) s_carry += wsum[15];
    __syncthreads();
  }
  if (threadIdx.x == 0) offsets[NN] = s_carry;
}

// ---------------------------------------------------------------- scatter edges into CSR slots
// also permutes edge_attr into CSR order as bf16 (PermEA, 16 bf16 = 8 uints per slot):
// turns k_agg's random eattr gathers into sequential reads.
__global__ void k_scatter(const int* __restrict__ eidx, const int* __restrict__ offsets,
                          int* __restrict__ cursor, int* __restrict__ srcs,
                          const float* __restrict__ eattr, unsigned int* __restrict__ PermEA) {
  int e = blockIdx.x * 256 + threadIdx.x;
  if (e < EE) {
    int s = eidx[e];
    int d = eidx[EE + e];
    int pos = offsets[d] + atomicAdd(&cursor[d], 1);
    srcs[pos] = s;
    const float4* ep = (const float4*)(eattr + (size_t)e * EDIM);
    float4 q0 = ep[0], q1 = ep[1], q2 = ep[2], q3 = ep[3];
    uint4 pa, pb;
    pa.x = (unsigned)bf_rne(q0.x) | ((unsigned)bf_rne(q0.y) << 16);
    pa.y = (unsigned)bf_rne(q0.z) | ((unsigned)bf_rne(q0.w) << 16);
    pa.z = (unsigned)bf_rne(q1.x) | ((unsigned)bf_rne(q1.y) << 16);
    pa.w = (unsigned)bf_rne(q1.z) | ((unsigned)bf_rne(q1.w) << 16);
    pb.x = (unsigned)bf_rne(q2.x) | ((unsigned)bf_rne(q2.y) << 16);
    pb.y = (unsigned)bf_rne(q2.z) | ((unsigned)bf_rne(q2.w) << 16);
    pb.z = (unsigned)bf_rne(q3.x) | ((unsigned)bf_rne(q3.y) << 16);
    pb.w = (unsigned)bf_rne(q3.z) | ((unsigned)bf_rne(q3.w) << 16);
    ((uint4*)PermEA)[(size_t)pos * 2] = pa;
    ((uint4*)PermEA)[(size_t)pos * 2 + 1] = pb;
  }
}

// ---------------------------------------------------------------- amp/att
__global__ void k_ampatt(const int* __restrict__ deg, const double* __restrict__ acc,
                         float* __restrict__ amp, float* __restrict__ att) {
  int n = blockIdx.x * 256 + threadIdx.x;
  if (n < NN) {
    float avg = (float)(acc[0] / (double)NN);
    float d = (float)deg[n];
    float logd = logf(fmaxf(d, 1.0f) + 1.0f);
    amp[n] = logd / avg;
    att[n] = avg / logd;
  }
}

// ---------------------------------------------------------------- per-layer prep
__global__ __launch_bounds__(256) void k_prep2(const float* __restrict__ We, const float* __restrict__ be,
                                               const float* __restrict__ Wpre, const float* __restrict__ bpre,
                                               const float* __restrict__ Wpost, const float* __restrict__ bpost,
                                               const float* __restrict__ Wlin, const float* __restrict__ blin,
                                               float* __restrict__ Mw, float* __restrict__ bconst,
                                               unsigned short* __restrict__ WcT_h, unsigned short* __restrict__ WcT_l,
                                               unsigned short* __restrict__ WxT_h, unsigned short* __restrict__ WxT_l,
                                               float* __restrict__ bcomb) {
  int id = blockIdx.x * 256 + threadIdx.x;
  if (id < 53248) {                      // WcombT
    int k = id >> 6, f = id & 63;
    float a = 0.0f;
    for (int j = 0; j < FF; j++) a += Wpost[(size_t)k * FF + j] * Wlin[j * FF + f];
    unsigned short h = bf_rne(a);
    WcT_h[f * 832 + k] = h;
    WcT_l[f * 832 + k] = bf_rne(a - bf_up(h));
  } else if (id < 61440) {               // WxT
    int lid = id - 53248;
    int j = lid >> 6, k = lid & 63;
    float v = (j < 64) ? Wpre[k * FF + j] : Wpre[(64 + k) * FF + (j - 64)];
    unsigned short h = bf_rne(v);
    WxT_h[j * 64 + k] = h;
    WxT_l[j * 64 + k] = bf_rne(v - bf_up(h));
  } else if (id < 62464) {               // Mw
    int lid = id - 61440;
    int k = lid >> 6, f = lid & 63;
    float a = 0.0f;
    for (int j = 0; j < FF; j++) a += We[k * FF + j] * Wpre[(128 + j) * FF + f];
    Mw[k * FF + f] = a;
  } else {                               // biases
    int f = threadIdx.x;
    if (blockIdx.x == 244 && f < 64) {
      float b = bpre[f];
      for (int j = 0; j < FF; j++) b += be[j] * Wpre[(128 + j) * FF + f];
      bconst[f] = b;
      float c = blin[f];
      for (int j = 0; j < FF; j++) c += bpost[j] * Wlin[j * FF + f];
      bcomb[f] = c;
    }
  }
}

// ---------------------------------------------------------------- [Xd|Xs] = x @ Wx  via bf16x3 MFMA
__global__ __launch_bounds__(256) void k_xform(const float* __restrict__ x,
                                               const unsigned short* __restrict__ WxT_h,
                                               const unsigned short* __restrict__ WxT_l,
                                               float* __restrict__ Xd, float* __restrict__ Xs) {
  __shared__ unsigned short Ah[64 * 72], Al[64 * 72];
  __shared__ unsigned short Bh[128 * 72], Bl[128 * 72];
  int t = threadIdx.x;
  int n0 = blockIdx.x * 64;
  // stage B (weights, [col][k] layout, row stride 72); each thread: 32 k-elems
  {
    int j = t >> 1, half = t & 1;
    const ushort4* srch = (const ushort4*)(WxT_h + j * 64 + half * 32);
    const ushort4* srcl = (const ushort4*)(WxT_l + j * 64 + half * 32);
    #pragma unroll
    for (int i = 0; i < 8; i++) {
      *(ushort4*)&Bh[j * 72 + half * 32 + i * 4] = srch[i];
      *(ushort4*)&Bl[j * 72 + half * 32 + i * 4] = srcl[i];
    }
  }
  // stage A (x rows, f32 -> hi/lo bf16)
  {
    int r = t >> 2, c0 = (t & 3) * 16;
    int n = n0 + r;
    bool rok = n < NN;
    const float4* src = (const float4*)(x + (size_t)n * FF + c0);
    #pragma unroll
    for (int c4 = 0; c4 < 4; c4++) {
      float4 v = rok ? src[c4] : make_float4(0.f, 0.f, 0.f, 0.f);
      ushort4 h4, l4;
      split4(v, h4, l4);
      *(ushort4*)&Ah[r * 72 + c0 + c4 * 4] = h4;
      *(ushort4*)&Al[r * 72 + c0 + c4 * 4] = l4;
    }
  }
  __syncthreads();
  int lane = t & 63;
  int l15 = lane & 15;
  int quad = lane >> 4;
  int w = __builtin_amdgcn_readfirstlane(t >> 6);
  int rbase = (w & 1) * 32;
  int cbase = (w >> 1) * 64;
  f32x4 acc[2][4];
  #pragma unroll
  for (int rt = 0; rt < 2; rt++)
    #pragma unroll
    for (int ct = 0; ct < 4; ct++) acc[rt][ct] = (f32x4){0.f, 0.f, 0.f, 0.f};

  #pragma unroll
  for (int ks = 0; ks < 2; ks++) {
    bf16x8 a_h[2], a_l[2];
    #pragma unroll
    for (int rt = 0; rt < 2; rt++) {
      int row = rbase + rt * 16 + l15;
      a_h[rt] = *(const bf16x8*)&Ah[row * 72 + ks * 32 + quad * 8];
      a_l[rt] = *(const bf16x8*)&Al[row * 72 + ks * 32 + quad * 8];
    }
    #pragma unroll
    for (int ct = 0; ct < 4; ct++) {
      int col = cbase + ct * 16 + l15;
      bf16x8 b_h = *(const bf16x8*)&Bh[col * 72 + ks * 32 + quad * 8];
      bf16x8 b_l = *(const bf16x8*)&Bl[col * 72 + ks * 32 + quad * 8];
      #pragma unroll
      for (int rt = 0; rt < 2; rt++) {
        acc[rt][ct] = __builtin_amdgcn_mfma_f32_16x16x32_bf16(a_h[rt], b_h, acc[rt][ct], 0, 0, 0);
        acc[rt][ct] = __builtin_amdgcn_mfma_f32_16x16x32_bf16(a_h[rt], b_l, acc[rt][ct], 0, 0, 0);
        acc[rt][ct] = __builtin_amdgcn_mfma_f32_16x16x32_bf16(a_l[rt], b_h, acc[rt][ct], 0, 0, 0);
      }
    }
  }
  // store: cols 0..63 -> Xd, 64..127 -> Xs
  #pragma unroll
  for (int rt = 0; rt < 2; rt++) {
    #pragma unroll
    for (int ct = 0; ct < 4; ct++) {
      int col = cbase + ct * 16 + l15;
      float* dst = (col < 64) ? (Xd + col) : (Xs + col - 64);
      #pragma unroll
      for (int reg = 0; reg < 4; reg++) {
        int n = n0 + rbase + rt * 16 + quad * 4 + reg;
        if (n < NN) dst[(size_t)n * FF] = acc[rt][ct][reg];
      }
    }
  }
}

// ---------------------------------------------------------------- per-node CSR aggregation (R4 structure + sequential bf16 PermEA)
__global__ __launch_bounds__(256) void k_agg(const int* __restrict__ srcs, const int* __restrict__ offsets,
                                             const unsigned int* __restrict__ PermEA,
                                             const float* __restrict__ Mw, const float* __restrict__ bconst,
                                             const float* __restrict__ Xd, const float* __restrict__ Xs,
                                             float* __restrict__ aggs) {
  int wid = __builtin_amdgcn_readfirstlane(threadIdx.x >> 6);
  int lane = threadIdx.x & 63;
  int n = blockIdx.x * 4 + wid;
  if (n >= NN) return;
  float mw[16];
  #pragma unroll
  for (int k = 0; k < 16; k++) mw[k] = Mw[k * FF + lane];
  float base_h = Xd[(size_t)n * FF + lane] + bconst[lane];
  int o0 = offsets[n], o1 = offsets[n + 1];
  float s = 0.f, sq = 0.f, mn = FLT_MAX, mx = -FLT_MAX;

  for (int base = o0; base < o1; base += 64) {
    int m = min(64, o1 - base);
    int sv = 0;
    if (base + lane < o1) sv = srcs[base + lane];
    for (int j = 0; j < m; j++) {
      int src = __shfl(sv, j);
      float xs = Xs[(size_t)src * FF + lane];
      const uint4* q = (const uint4*)PermEA + (size_t)(base + j) * 2;
      uint4 qa = q[0], qb = q[1];
      float et = blo(qa.x) * mw[0]  + bhi(qa.x) * mw[1]
               + blo(qa.y) * mw[2]  + bhi(qa.y) * mw[3]
               + blo(qa.z) * mw[4]  + bhi(qa.z) * mw[5]
               + blo(qa.w) * mw[6]  + bhi(qa.w) * mw[7]
               + blo(qb.x) * mw[8]  + bhi(qb.x) * mw[9]
               + blo(qb.y) * mw[10] + bhi(qb.y) * mw[11]
               + blo(qb.z) * mw[12] + bhi(qb.z) * mw[13]
               + blo(qb.w) * mw[14] + bhi(qb.w) * mw[15];
      float h = base_h + xs + et;
      s += h;
      sq += h * h;
      mn = fminf(mn, h);
      mx = fmaxf(mx, h);
    }
  }
  float d = (float)(o1 - o0);
  float dc = fmaxf(d, 1.0f);
  float mean = s / dc;
  float msq = sq / dc;
  float sd = sqrtf(fmaxf(msq - mean * mean, 0.0f) + 1e-5f);
  bool has = d > 0.0f;
  float vmn = has ? mn : 0.0f;
  float vmx = has ? mx : 0.0f;
  size_t b = (size_t)n * 256;
  aggs[b + lane] = mean;
  aggs[b + 64 + lane] = vmn;
  aggs[b + 128 + lane] = vmx;
  aggs[b + 192 + lane] = sd;
}

// ---------------------------------------------------------------- y = A @ Wcomb + bcomb  (bf16x3 MFMA) + BN partials
__global__ __launch_bounds__(256) void k_post(const float* __restrict__ x, const float* __restrict__ aggs,
                                              const float* __restrict__ amp, const float* __restrict__ att,
                                              const unsigned short* __restrict__ WcT_h,
                                              const unsigned short* __restrict__ WcT_l,
                                              const float* __restrict__ bcomb,
                                              float* __restrict__ y, float* __restrict__ partials) {
  __shared__ unsigned short Ah[64 * 72], Al[64 * 72];
  __shared__ unsigned short Bh[64 * 72], Bl[64 * 72];
  __shared__ float red_s[4][32], red_q[4][32];
  int t = threadIdx.x;
  int n0 = blockIdx.x * 64;
  int lane = t & 63;
  int l15 = lane & 15;
  int quad = lane >> 4;
  int w = __builtin_amdgcn_readfirstlane(t >> 6);
  int rbase = (w & 1) * 32;
  int cbase = (w >> 1) * 32;

  int ar = t >> 2;                // staging row (A) / col (B)
  int ac0 = (t & 3) * 16;
  int an = n0 + ar;
  bool rok = an < NN;
  float sc_amp = rok ? amp[an] : 0.f;
  float sc_att = rok ? att[an] : 0.f;
  const float* xrow = x + (size_t)an * FF;
  const float* arow = aggs + (size_t)an * 256;

  f32x4 acc[2][2];
  #pragma unroll
  for (int rt = 0; rt < 2; rt++)
    #pragma unroll
    for (int ct = 0; ct < 2; ct++) acc[rt][ct] = (f32x4){0.f, 0.f, 0.f, 0.f};

  for (int kc = 0; kc < 13; kc++) {
    // ---- stage A chunk [64 rows][64 k]
    const float* srcb;
    float scale = 1.0f;
    if (kc == 0) {
      srcb = xrow;
    } else {
      int kcm = kc - 1;
      srcb = arow + (kcm & 3) * 64;
      int sel = kcm >> 2;
      scale = (sel == 0) ? 1.0f : (sel == 1 ? sc_amp : sc_att);
    }
    #pragma unroll
    for (int c4 = 0; c4 < 4; c4++) {
      float4 v = rok ? *(const float4*)(srcb + ac0 + c4 * 4) : make_float4(0.f, 0.f, 0.f, 0.f);
      v.x *= scale; v.y *= scale; v.z *= scale; v.w *= scale;
      ushort4 h4, l4;
      split4(v, h4, l4);
      *(ushort4*)&Ah[ar * 72 + ac0 + c4 * 4] = h4;
      *(ushort4*)&Al[ar * 72 + ac0 + c4 * 4] = l4;
    }
    // ---- stage B chunk [64 cols][64 k]; each thread: 16 k-elems
    {
      int kbase = kc * 64;
      const ushort4* sh = (const ushort4*)(WcT_h + ar * 832 + kbase + ac0);
      const ushort4* sl = (const ushort4*)(WcT_l + ar * 832 + kbase + ac0);
      #pragma unroll
      for (int i = 0; i < 4; i++) {
        *(ushort4*)&Bh[ar * 72 + ac0 + i * 4] = sh[i];
        *(ushort4*)&Bl[ar * 72 + ac0 + i * 4] = sl[i];
      }
    }
    __syncthreads();
    #pragma unroll
    for (int ks = 0; ks < 2; ks++) {
      bf16x8 a_h[2], a_l[2], b_h[2], b_l[2];
      #pragma unroll
      for (int rt = 0; rt < 2; rt++) {
        int row = rbase + rt * 16 + l15;
        a_h[rt] = *(const bf16x8*)&Ah[row * 72 + ks * 32 + quad * 8];
        a_l[rt] = *(const bf16x8*)&Al[row * 72 + ks * 32 + quad * 8];
      }
      #pragma unroll
      for (int ct = 0; ct < 2; ct++) {
        int col = cbase + ct * 16 + l15;
        b_h[ct] = *(const bf16x8*)&Bh[col * 72 + ks * 32 + quad * 8];
        b_l[ct] = *(const bf16x8*)&Bl[col * 72 + ks * 32 + quad * 8];
      }
      #pragma unroll
      for (int rt = 0; rt < 2; rt++)
        #pragma unroll
        for (int ct = 0; ct < 2; ct++) {
          acc[rt][ct] = __builtin_amdgcn_mfma_f32_16x16x32_bf16(a_h[rt], b_h[ct], acc[rt][ct], 0, 0, 0);
          acc[rt][ct] = __builtin_amdgcn_mfma_f32_16x16x32_bf16(a_h[rt], b_l[ct], acc[rt][ct], 0, 0, 0);
          acc[rt][ct] = __builtin_amdgcn_mfma_f32_16x16x32_bf16(a_l[rt], b_h[ct], acc[rt][ct], 0, 0, 0);
        }
    }
    __syncthreads();
  }

  // ---- epilogue: bias, store y, BN partials
  float ps[2] = {0.f, 0.f}, pq[2] = {0.f, 0.f};
  #pragma unroll
  for (int ct = 0; ct < 2; ct++) {
    int col = cbase + ct * 16 + l15;
    float bc = bcomb[col];
    #pragma unroll
    for (int rt = 0; rt < 2; rt++) {
      #pragma unroll
      for (int reg = 0; reg < 4; reg++) {
        int n = n0 + rbase + rt * 16 + quad * 4 + reg;
        float v = acc[rt][ct][reg] + bc;
        if (n < NN) {
          y[(size_t)n * FF + col] = v;
          ps[ct] += v;
          pq[ct] += v * v;
        }
      }
    }
  }
  #pragma unroll
  for (int ct = 0; ct < 2; ct++) {
    ps[ct] += __shfl_xor(ps[ct], 16);
    ps[ct] += __shfl_xor(ps[ct], 32);
    pq[ct] += __shfl_xor(pq[ct], 16);
    pq[ct] += __shfl_xor(pq[ct], 32);
  }
  if (quad == 0) {
    #pragma unroll
    for (int ct = 0; ct < 2; ct++) {
      red_s[w][ct * 16 + l15] = ps[ct];
      red_q[w][ct * 16 + l15] = pq[ct];
    }
  }
  __syncthreads();
  if (t < 64) {
    float ss, qq;
    if (t < 32) { ss = red_s[0][t] + red_s[1][t]; qq = red_q[0][t] + red_q[1][t]; }
    else        { ss = red_s[2][t - 32] + red_s[3][t - 32]; qq = red_q[2][t - 32] + red_q[3][t - 32]; }
    partials[(size_t)blockIdx.x * 128 + t] = ss;
    partials[(size_t)blockIdx.x * 128 + 64 + t] = qq;
  }
}

// ---------------------------------------------------------------- reduce BN partials -> scb (scale, offset)
__global__ __launch_bounds__(1024) void k_bnfin(const float* __restrict__ partials,
                                                const float* __restrict__ gamma, const float* __restrict__ beta,
                                                float* __restrict__ scb) {
  __shared__ float red[1024];
  __shared__ double tot[128];
  int t = threadIdx.x;
  int c = t & 127, seg = t >> 7;
  float s = 0.f;
  for (int i = seg; i < NB64; i += 8) s += partials[(size_t)i * 128 + c];
  red[t] = s;
  __syncthreads();
  if (t < 128) {
    double d = 0.0;
    #pragma unroll
    for (int sg = 0; sg < 8; sg++) d += (double)red[sg * 128 + t];
    tot[t] = d;
  }
  __syncthreads();
  if (t < 64) {
    double mu = tot[t] / (double)NN;
    double var = tot[64 + t] / (double)NN - mu * mu;
    float sc = gamma[t] * rsqrtf((float)fmax(var, 0.0) + 1e-5f);
    scb[t] = sc;
    scb[64 + t] = beta[t] - (float)mu * sc;
  }
}

// ---------------------------------------------------------------- BN apply + relu, elementwise float4 (in-place safe)
__global__ __launch_bounds__(256) void k_bnapply(const float* __restrict__ y, const float* __restrict__ scb,
                                                 float* __restrict__ xout) {
  int idx = blockIdx.x * 256 + threadIdx.x;  // over NN*16 float4s
  if (idx >= NN * 16) return;
  int f4 = idx & 15;
  float4 v = ((const float4*)y)[idx];
  float4 sc = ((const float4*)scb)[f4];
  float4 of = ((const float4*)(scb + 64))[f4];
  v.x = fmaxf(v.x * sc.x + of.x, 0.0f);
  v.y = fmaxf(v.y * sc.y + of.y, 0.0f);
  v.z = fmaxf(v.z * sc.z + of.z, 0.0f);
  v.w = fmaxf(v.w * sc.w + of.w, 0.0f);
  ((float4*)xout)[idx] = v;
}

// ---------------------------------------------------------------- pooling over sorted batch
__global__ __launch_bounds__(256) void k_pool(const float* __restrict__ x, const int* __restrict__ batch,
                                              float* __restrict__ psum, float* __restrict__ cnt) {
  int lane = threadIdx.x & 63;
  int wv = threadIdx.x >> 6;
  int wglobal = blockIdx.x * 4 + wv;
  int nw = gridDim.x * 4;
  int per = (NN + nw - 1) / nw;
  int n0 = wglobal * per;
  int n1 = min(n0 + per, NN);
  if (n0 >= n1) return;
  int gcur = batch[n0];
  float acc = 0.0f;
  int count = 0;
  for (int n = n0; n < n1; n++) {
    int g = batch[n];
    float v = x[(size_t)n * FF + lane];
    if (g != gcur) {
      atomicAdd(&psum[gcur * FF + lane], acc);
      if (lane == 0) atomicAdd(&cnt[gcur], (float)count);
      gcur = g; acc = 0.0f; count = 0;
    }
    acc += v;
    count++;
  }
  atomicAdd(&psum[gcur * FF + lane], acc);
  if (lane == 0) atomicAdd(&cnt[gcur], (float)count);
}

// ---------------------------------------------------------------- final MLP over pooled means
__global__ void k_final(const float* __restrict__ psum, const float* __restrict__ cnt,
                        const float* __restrict__ W1, const float* __restrict__ b1,
                        const float* __restrict__ W2, const float* __restrict__ b2, float* __restrict__ out) {
  int g = threadIdx.x;
  if (g >= GG) return;
  float c = fmaxf(cnt[g], 1.0f);
  float gm[64];
  #pragma unroll
  for (int i = 0; i < 64; i++) gm[i] = psum[g * FF + i] / c;
  float o = b2[0];
  for (int h = 0; h < 40; h++) {
    float a = b1[h];
    #pragma unroll
    for (int i = 0; i < 64; i++) a += gm[i] * W1[i * 40 + h];
    o += fmaxf(a, 0.0f) * W2[h];
  }
  out[g] = o;
}

// ================================================================ launch
extern "C" void kernel_launch(void* const* d_in, const int* in_sizes, int n_in,
                              void* d_out, int out_size, void* d_ws, size_t ws_size,
                              hipStream_t stream) {
  (void)in_sizes; (void)n_in; (void)out_size; (void)ws_size;
  const float* x0    = (const float*)d_in[0];
  const float* eattr = (const float*)d_in[1];
  const float* We    = (const float*)d_in[2];
  const float* be    = (const float*)d_in[3];
  const float* Wpre  = (const float*)d_in[4];
  const float* bpre  = (const float*)d_in[5];
  const float* Wpost = (const float*)d_in[6];
  const float* bpost = (const float*)d_in[7];
  const float* Wlin  = (const float*)d_in[8];
  const float* blin  = (const float*)d_in[9];
  const float* gamma = (const float*)d_in[10];
  const float* beta  = (const float*)d_in[11];
  const float* W1    = (const float*)d_in[12];
  const float* b1    = (const float*)d_in[13];
  const float* W2    = (const float*)d_in[14];
  const float* b2    = (const float*)d_in[15];
  const int* eidx    = (const int*)d_in[16];
  const int* batch   = (const int*)d_in[17];
  float* out = (float*)d_out;

  char* w = (char*)d_ws;
  size_t off = 0;
  auto alloc = [&](size_t bytes) -> void* {
    void* p = w + off;
    off += bytes;
    off = (off + 255) & ~(size_t)255;
    return p;
  };
  int*    deg     = (int*)alloc(NN * sizeof(int));
  int*    offsets = (int*)alloc((NN + 1) * sizeof(int));
  int*    cursor  = (int*)alloc(NN * sizeof(int));
  int*    srcs    = (int*)alloc(EE * sizeof(int));
  unsigned int* PermEA = (unsigned int*)alloc((size_t)EE * 8 * sizeof(unsigned int));  // 16 bf16/edge
  double* avgacc  = (double*)alloc(sizeof(double));
  float*  amp     = (float*)alloc(NN * sizeof(float));
  float*  att     = (float*)alloc(NN * sizeof(float));
  float*  Mw      = (float*)alloc(EDIM * FF * sizeof(float));
  float*  bconst  = (float*)alloc(FF * sizeof(float));
  float*  bcomb   = (float*)alloc(FF * sizeof(float));
  float*  scb     = (float*)alloc(2 * FF * sizeof(float));
  unsigned short* WcT_h = (unsigned short*)alloc(FF * 832 * sizeof(unsigned short));
  unsigned short* WcT_l = (unsigned short*)alloc(FF * 832 * sizeof(unsigned short));
  unsigned short* WxT_h = (unsigned short*)alloc(128 * 64 * sizeof(unsigned short));
  unsigned short* WxT_l = (unsigned short*)alloc(128 * 64 * sizeof(unsigned short));
  float*  partials = (float*)alloc((size_t)NB64 * 128 * sizeof(float));
  float*  Xd      = (float*)alloc((size_t)NN * FF * sizeof(float));
  float*  Xs      = (float*)alloc((size_t)NN * FF * sizeof(float));
  float*  aggs    = (float*)alloc((size_t)NN * 256 * sizeof(float));
  float*  ybuf    = (float*)alloc((size_t)NN * FF * sizeof(float));   // also serves as x for next layer (in-place BN)
  float*  psum    = (float*)alloc((GG * FF + GG) * sizeof(float));
  float*  cnt     = psum + GG * FF;

  hipMemsetAsync(deg, 0, NN * sizeof(int), stream);
  hipMemsetAsync(cursor, 0, NN * sizeof(int), stream);
  hipMemsetAsync(avgacc, 0, sizeof(double), stream);
  hipMemsetAsync(psum, 0, (GG * FF + GG) * sizeof(float), stream);

  k_deg<<<(EE + 255) / 256, 256, 0, stream>>>(eidx, deg);
  k_avglog<<<(NN + 255) / 256, 256, 0, stream>>>(deg, avgacc);
  k_scan<<<1, 1024, 0, stream>>>(deg, offsets);
  k_scatter<<<(EE + 255) / 256, 256, 0, stream>>>(eidx, offsets, cursor, srcs, eattr, PermEA);
  k_ampatt<<<(NN + 255) / 256, 256, 0, stream>>>(deg, avgacc, amp, att);

  const float* xin = x0;
  for (int l = 0; l < 2; l++) {
    k_prep2<<<245, 256, 0, stream>>>(We + l * EDIM * FF, be + l * FF, Wpre + (size_t)l * 3 * FF * FF,
                                     bpre + l * FF, Wpost + (size_t)l * 832 * FF, bpost + l * FF,
                                     Wlin + l * FF * FF, blin + l * FF,
                                     Mw, bconst, WcT_h, WcT_l, WxT_h, WxT_l, bcomb);
    k_xform<<<NB64, 256, 0, stream>>>(xin, WxT_h, WxT_l, Xd, Xs);
    k_agg<<<(NN + 3) / 4, 256, 0, stream>>>(srcs, offsets, PermEA, Mw, bconst, Xd, Xs, aggs);
    k_post<<<NB64, 256, 0, stream>>>(xin, aggs, amp, att, WcT_h, WcT_l, bcomb, ybuf, partials);
    k_bnfin<<<1, 1024, 0, stream>>>(partials, gamma + l * FF, beta + l * FF, scb);
    k_bnapply<<<(NN * 16 + 255) / 256, 256, 0, stream>>>(ybuf, scb, ybuf);
    xin = ybuf;
  }
  k_pool<<<200, 256, 0, stream>>>(ybuf, batch, psum, cnt);
  k_final<<<1, 64, 0, stream>>>(psum, cnt, W1, b1, W2, b2, out);
}

// Round 10
// 591.847 us; speedup vs baseline: 1.2550x; 1.0817x over previous
//
#include <hip/hip_runtime.h>
#include <math.h>
#include <float.h>

#define NN 50000
#define EE 800000
#define FF 64
#define EDIM 16
#define GG 64
#define NB64 782   // ceil(NN/64)
#define NSB 196    // ceil(NN/256) scan blocks

typedef short bf16x8 __attribute__((ext_vector_type(8)));
typedef float f32x4 __attribute__((ext_vector_type(4)));

__device__ inline unsigned short bf_rne(float v) {
  unsigned int u = __float_as_uint(v);
  unsigned int r = (u + 0x7FFFu + ((u >> 16) & 1u)) >> 16;
  return (unsigned short)r;
}
__device__ inline float bf_up(unsigned short h) {
  return __uint_as_float(((unsigned int)h) << 16);
}
__device__ inline void split4(float4 v, ushort4& h, ushort4& l) {
  h.x = bf_rne(v.x); h.y = bf_rne(v.y); h.z = bf_rne(v.z); h.w = bf_rne(v.w);
  l.x = bf_rne(v.x - bf_up(h.x));
  l.y = bf_rne(v.y - bf_up(h.y));
  l.z = bf_rne(v.z - bf_up(h.z));
  l.w = bf_rne(v.w - bf_up(h.w));
}
__device__ inline float blo(unsigned int u) { return __uint_as_float(u << 16); }
__device__ inline float bhi(unsigned int u) { return __uint_as_float(u & 0xFFFF0000u); }

// ---------------------------------------------------------------- degree
__global__ void k_deg(const int* __restrict__ eidx, int* __restrict__ deg) {
  int e = blockIdx.x * 256 + threadIdx.x;
  if (e < EE) atomicAdd(&deg[eidx[EE + e]], 1);
}

// ---------------------------------------------------------------- scan pass A: per-block exclusive scan + block sums + log-deg sums
__global__ __launch_bounds__(256) void k_scanA(const int* __restrict__ deg, int* __restrict__ offsets,
                                               int* __restrict__ bsum, float* __restrict__ lsum) {
  __shared__ int ws[4];
  __shared__ float lw[4];
  int t = threadIdx.x;
  int lane = t & 63;
  int wv = t >> 6;
  int i = blockIdx.x * 256 + t;
  int v = (i < NN) ? deg[i] : 0;
  float lg = (i < NN) ? logf((float)v + 1.0f) : 0.0f;
  int x = v;
  #pragma unroll
  for (int o = 1; o < 64; o <<= 1) {
    int y = __shfl_up(x, o);
    if (lane >= o) x += y;
  }
  #pragma unroll
  for (int o = 1; o < 64; o <<= 1) lg += __shfl_xor(lg, o);
  if (lane == 63) ws[wv] = x;
  if (lane == 0) lw[wv] = lg;
  __syncthreads();
  int pre = 0;
  for (int k = 0; k < wv; k++) pre += ws[k];
  if (i < NN) offsets[i] = pre + x - v;  // block-local exclusive
  if (t == 0) {
    bsum[blockIdx.x] = ws[0] + ws[1] + ws[2] + ws[3];
    lsum[blockIdx.x] = lw[0] + lw[1] + lw[2] + lw[3];
  }
}

// ---------------------------------------------------------------- scan pass B: scan 196 block sums; avg log; identity scb
__global__ __launch_bounds__(256) void k_scanB(const int* __restrict__ bsum, const float* __restrict__ lsum,
                                               int* __restrict__ bpref, float* __restrict__ meta,
                                               float* __restrict__ scbA) {
  __shared__ int ws[4];
  __shared__ float lw[4];
  int t = threadIdx.x;
  int lane = t & 63;
  int wv = t >> 6;
  int v = (t < NSB) ? bsum[t] : 0;
  float lg = (t < NSB) ? lsum[t] : 0.0f;
  int x = v;
  #pragma unroll
  for (int o = 1; o < 64; o <<= 1) {
    int y = __shfl_up(x, o);
    if (lane >= o) x += y;
  }
  #pragma unroll
  for (int o = 1; o < 64; o <<= 1) lg += __shfl_xor(lg, o);
  if (lane == 63) ws[wv] = x;
  if (lane == 0) lw[wv] = lg;
  __syncthreads();
  int pre = 0;
  for (int k = 0; k < wv; k++) pre += ws[k];
  if (t < NSB) bpref[t] = pre + x - v;   // exclusive prefix of block sums
  if (t == 0) meta[0] = (lw[0] + lw[1] + lw[2] + lw[3]) / (float)NN;
  if (t < 64) { scbA[t] = 1.0f; scbA[64 + t] = 0.0f; }
  if (t == 0) scbA[128] = -FLT_MAX;      // no relu for raw input
}

// ---------------------------------------------------------------- scan pass C: add prefix; amp/att
__global__ __launch_bounds__(256) void k_scanC(int* __restrict__ offsets, const int* __restrict__ bpref,
                                               const int* __restrict__ deg, const float* __restrict__ meta,
                                               float* __restrict__ amp, float* __restrict__ att) {
  int i = blockIdx.x * 256 + threadIdx.x;
  if (i < NN) {
    offsets[i] += bpref[blockIdx.x];
    float d = (float)deg[i];
    float avg = meta[0];
    float logd = logf(fmaxf(d, 1.0f) + 1.0f);
    amp[i] = logd / avg;
    att[i] = avg / logd;
  }
  if (i == 0) offsets[NN] = EE;
}

// ---------------------------------------------------------------- scatter edges into CSR slots + permute eattr to CSR order (bf16)
__global__ void k_scatter(const int* __restrict__ eidx, const int* __restrict__ offsets,
                          int* __restrict__ cursor, int* __restrict__ srcs,
                          const float* __restrict__ eattr, unsigned int* __restrict__ PermEA) {
  int e = blockIdx.x * 256 + threadIdx.x;
  if (e < EE) {
    int s = eidx[e];
    int d = eidx[EE + e];
    int pos = offsets[d] + atomicAdd(&cursor[d], 1);
    srcs[pos] = s;
    const float4* ep = (const float4*)(eattr + (size_t)e * EDIM);
    float4 q0 = ep[0], q1 = ep[1], q2 = ep[2], q3 = ep[3];
    uint4 pa, pb;
    pa.x = (unsigned)bf_rne(q0.x) | ((unsigned)bf_rne(q0.y) << 16);
    pa.y = (unsigned)bf_rne(q0.z) | ((unsigned)bf_rne(q0.w) << 16);
    pa.z = (unsigned)bf_rne(q1.x) | ((unsigned)bf_rne(q1.y) << 16);
    pa.w = (unsigned)bf_rne(q1.z) | ((unsigned)bf_rne(q1.w) << 16);
    pb.x = (unsigned)bf_rne(q2.x) | ((unsigned)bf_rne(q2.y) << 16);
    pb.y = (unsigned)bf_rne(q2.z) | ((unsigned)bf_rne(q2.w) << 16);
    pb.z = (unsigned)bf_rne(q3.x) | ((unsigned)bf_rne(q3.y) << 16);
    pb.w = (unsigned)bf_rne(q3.z) | ((unsigned)bf_rne(q3.w) << 16);
    ((uint4*)PermEA)[(size_t)pos * 2] = pa;
    ((uint4*)PermEA)[(size_t)pos * 2 + 1] = pb;
  }
}

// ---------------------------------------------------------------- per-layer prep
__global__ __launch_bounds__(256) void k_prep2(const float* __restrict__ We, const float* __restrict__ be,
                                               const float* __restrict__ Wpre, const float* __restrict__ bpre,
                                               const float* __restrict__ Wpost, const float* __restrict__ bpost,
                                               const float* __restrict__ Wlin, const float* __restrict__ blin,
                                               float* __restrict__ Mw, float* __restrict__ bconst,
                                               unsigned short* __restrict__ WcT_h, unsigned short* __restrict__ WcT_l,
                                               unsigned short* __restrict__ WxT_h, unsigned short* __restrict__ WxT_l,
                                               float* __restrict__ bcomb) {
  int id = blockIdx.x * 256 + threadIdx.x;
  if (id < 53248) {                      // WcombT
    int k = id >> 6, f = id & 63;
    float a = 0.0f;
    for (int j = 0; j < FF; j++) a += Wpost[(size_t)k * FF + j] * Wlin[j * FF + f];
    unsigned short h = bf_rne(a);
    WcT_h[f * 832 + k] = h;
    WcT_l[f * 832 + k] = bf_rne(a - bf_up(h));
  } else if (id < 61440) {               // WxT
    int lid = id - 53248;
    int j = lid >> 6, k = lid & 63;
    float v = (j < 64) ? Wpre[k * FF + j] : Wpre[(64 + k) * FF + (j - 64)];
    unsigned short h = bf_rne(v);
    WxT_h[j * 64 + k] = h;
    WxT_l[j * 64 + k] = bf_rne(v - bf_up(h));
  } else if (id < 62464) {               // Mw
    int lid = id - 61440;
    int k = lid >> 6, f = lid & 63;
    float a = 0.0f;
    for (int j = 0; j < FF; j++) a += We[k * FF + j] * Wpre[(128 + j) * FF + f];
    Mw[k * FF + f] = a;
  } else {                               // biases
    int f = threadIdx.x;
    if (blockIdx.x == 244 && f < 64) {
      float b = bpre[f];
      for (int j = 0; j < FF; j++) b += be[j] * Wpre[(128 + j) * FF + f];
      bconst[f] = b;
      float c = blin[f];
      for (int j = 0; j < FF; j++) c += bpost[j] * Wlin[j * FF + f];
      bcomb[f] = c;
    }
  }
}

// ---------------------------------------------------------------- [Xd|Xs] = bn(x) @ Wx  via bf16x3 MFMA (BN fused into staging)
__global__ __launch_bounds__(256) void k_xform(const float* __restrict__ x, const float* __restrict__ scb,
                                               const unsigned short* __restrict__ WxT_h,
                                               const unsigned short* __restrict__ WxT_l,
                                               float* __restrict__ Xd, float* __restrict__ Xs) {
  __shared__ unsigned short Ah[64 * 72], Al[64 * 72];
  __shared__ unsigned short Bh[128 * 72], Bl[128 * 72];
  int t = threadIdx.x;
  int n0 = blockIdx.x * 64;
  // stage B (weights, [col][k] layout, row stride 72); each thread: 32 k-elems
  {
    int j = t >> 1, half = t & 1;
    const ushort4* srch = (const ushort4*)(WxT_h + j * 64 + half * 32);
    const ushort4* srcl = (const ushort4*)(WxT_l + j * 64 + half * 32);
    #pragma unroll
    for (int i = 0; i < 8; i++) {
      *(ushort4*)&Bh[j * 72 + half * 32 + i * 4] = srch[i];
      *(ushort4*)&Bl[j * 72 + half * 32 + i * 4] = srcl[i];
    }
  }
  // stage A (bn(x) rows, f32 -> hi/lo bf16)
  {
    int r = t >> 2, c0 = (t & 3) * 16;
    int n = n0 + r;
    bool rok = n < NN;
    const float4* src = (const float4*)(x + (size_t)n * FF + c0);
    float flr = scb[128];
    #pragma unroll
    for (int c4 = 0; c4 < 4; c4++) {
      float4 v = rok ? src[c4] : make_float4(0.f, 0.f, 0.f, 0.f);
      float4 sc = ((const float4*)scb)[(c0 >> 2) + c4];
      float4 of = ((const float4*)(scb + 64))[(c0 >> 2) + c4];
      v.x = fmaxf(v.x * sc.x + of.x, flr);
      v.y = fmaxf(v.y * sc.y + of.y, flr);
      v.z = fmaxf(v.z * sc.z + of.z, flr);
      v.w = fmaxf(v.w * sc.w + of.w, flr);
      ushort4 h4, l4;
      split4(v, h4, l4);
      *(ushort4*)&Ah[r * 72 + c0 + c4 * 4] = h4;
      *(ushort4*)&Al[r * 72 + c0 + c4 * 4] = l4;
    }
  }
  __syncthreads();
  int lane = t & 63;
  int l15 = lane & 15;
  int quad = lane >> 4;
  int w = __builtin_amdgcn_readfirstlane(t >> 6);
  int rbase = (w & 1) * 32;
  int cbase = (w >> 1) * 64;
  f32x4 acc[2][4];
  #pragma unroll
  for (int rt = 0; rt < 2; rt++)
    #pragma unroll
    for (int ct = 0; ct < 4; ct++) acc[rt][ct] = (f32x4){0.f, 0.f, 0.f, 0.f};

  #pragma unroll
  for (int ks = 0; ks < 2; ks++) {
    bf16x8 a_h[2], a_l[2];
    #pragma unroll
    for (int rt = 0; rt < 2; rt++) {
      int row = rbase + rt * 16 + l15;
      a_h[rt] = *(const bf16x8*)&Ah[row * 72 + ks * 32 + quad * 8];
      a_l[rt] = *(const bf16x8*)&Al[row * 72 + ks * 32 + quad * 8];
    }
    #pragma unroll
    for (int ct = 0; ct < 4; ct++) {
      int col = cbase + ct * 16 + l15;
      bf16x8 b_h = *(const bf16x8*)&Bh[col * 72 + ks * 32 + quad * 8];
      bf16x8 b_l = *(const bf16x8*)&Bl[col * 72 + ks * 32 + quad * 8];
      #pragma unroll
      for (int rt = 0; rt < 2; rt++) {
        acc[rt][ct] = __builtin_amdgcn_mfma_f32_16x16x32_bf16(a_h[rt], b_h, acc[rt][ct], 0, 0, 0);
        acc[rt][ct] = __builtin_amdgcn_mfma_f32_16x16x32_bf16(a_h[rt], b_l, acc[rt][ct], 0, 0, 0);
        acc[rt][ct] = __builtin_amdgcn_mfma_f32_16x16x32_bf16(a_l[rt], b_h, acc[rt][ct], 0, 0, 0);
      }
    }
  }
  // store: cols 0..63 -> Xd, 64..127 -> Xs
  #pragma unroll
  for (int rt = 0; rt < 2; rt++) {
    #pragma unroll
    for (int ct = 0; ct < 4; ct++) {
      int col = cbase + ct * 16 + l15;
      float* dst = (col < 64) ? (Xd + col) : (Xs + col - 64);
      #pragma unroll
      for (int reg = 0; reg < 4; reg++) {
        int n = n0 + rbase + rt * 16 + quad * 4 + reg;
        if (n < NN) dst[(size_t)n * FF] = acc[rt][ct][reg];
      }
    }
  }
}

// ---------------------------------------------------------------- per-node CSR aggregation (sequential bf16 PermEA)
__global__ __launch_bounds__(256) void k_agg(const int* __restrict__ srcs, const int* __restrict__ offsets,
                                             const unsigned int* __restrict__ PermEA,
                                             const float* __restrict__ Mw, const float* __restrict__ bconst,
                                             const float* __restrict__ Xd, const float* __restrict__ Xs,
                                             float* __restrict__ aggs) {
  int wid = __builtin_amdgcn_readfirstlane(threadIdx.x >> 6);
  int lane = threadIdx.x & 63;
  int n = blockIdx.x * 4 + wid;
  if (n >= NN) return;
  float mw[16];
  #pragma unroll
  for (int k = 0; k < 16; k++) mw[k] = Mw[k * FF + lane];
  float base_h = Xd[(size_t)n * FF + lane] + bconst[lane];
  int o0 = offsets[n], o1 = offsets[n + 1];
  float s = 0.f, sq = 0.f, mn = FLT_MAX, mx = -FLT_MAX;

  for (int base = o0; base < o1; base += 64) {
    int m = min(64, o1 - base);
    int sv = 0;
    if (base + lane < o1) sv = srcs[base + lane];
    for (int j = 0; j < m; j++) {
      int src = __shfl(sv, j);
      float xs = Xs[(size_t)src * FF + lane];
      const uint4* q = (const uint4*)PermEA + (size_t)(base + j) * 2;
      uint4 qa = q[0], qb = q[1];
      float et = blo(qa.x) * mw[0]  + bhi(qa.x) * mw[1]
               + blo(qa.y) * mw[2]  + bhi(qa.y) * mw[3]
               + blo(qa.z) * mw[4]  + bhi(qa.z) * mw[5]
               + blo(qa.w) * mw[6]  + bhi(qa.w) * mw[7]
               + blo(qb.x) * mw[8]  + bhi(qb.x) * mw[9]
               + blo(qb.y) * mw[10] + bhi(qb.y) * mw[11]
               + blo(qb.z) * mw[12] + bhi(qb.z) * mw[13]
               + blo(qb.w) * mw[14] + bhi(qb.w) * mw[15];
      float h = base_h + xs + et;
      s += h;
      sq += h * h;
      mn = fminf(mn, h);
      mx = fmaxf(mx, h);
    }
  }
  float d = (float)(o1 - o0);
  float dc = fmaxf(d, 1.0f);
  float mean = s / dc;
  float msq = sq / dc;
  float sd = sqrtf(fmaxf(msq - mean * mean, 0.0f) + 1e-5f);
  bool has = d > 0.0f;
  float vmn = has ? mn : 0.0f;
  float vmx = has ? mx : 0.0f;
  size_t b = (size_t)n * 256;
  aggs[b + lane] = mean;
  aggs[b + 64 + lane] = vmn;
  aggs[b + 128 + lane] = vmx;
  aggs[b + 192 + lane] = sd;
}

// ---------------------------------------------------------------- y = [bn(x),scaled aggs] @ Wcomb + bcomb (bf16x3 MFMA) + BN partials
__global__ __launch_bounds__(256) void k_post(const float* __restrict__ x, const float* __restrict__ scb,
                                              const float* __restrict__ aggs,
                                              const float* __restrict__ amp, const float* __restrict__ att,
                                              const unsigned short* __restrict__ WcT_h,
                                              const unsigned short* __restrict__ WcT_l,
                                              const float* __restrict__ bcomb,
                                              float* __restrict__ y, float* __restrict__ partials) {
  __shared__ unsigned short Ah[64 * 72], Al[64 * 72];
  __shared__ unsigned short Bh[64 * 72], Bl[64 * 72];
  __shared__ float red_s[4][32], red_q[4][32];
  int t = threadIdx.x;
  int n0 = blockIdx.x * 64;
  int lane = t & 63;
  int l15 = lane & 15;
  int quad = lane >> 4;
  int w = __builtin_amdgcn_readfirstlane(t >> 6);
  int rbase = (w & 1) * 32;
  int cbase = (w >> 1) * 32;

  int ar = t >> 2;                // staging row (A) / col (B)
  int ac0 = (t & 3) * 16;
  int an = n0 + ar;
  bool rok = an < NN;
  float sc_amp = rok ? amp[an] : 0.f;
  float sc_att = rok ? att[an] : 0.f;
  const float* xrow = x + (size_t)an * FF;
  const float* arow = aggs + (size_t)an * 256;
  float flr = scb[128];

  f32x4 acc[2][2];
  #pragma unroll
  for (int rt = 0; rt < 2; rt++)
    #pragma unroll
    for (int ct = 0; ct < 2; ct++) acc[rt][ct] = (f32x4){0.f, 0.f, 0.f, 0.f};

  for (int kc = 0; kc < 13; kc++) {
    // ---- stage A chunk [64 rows][64 k]
    if (kc == 0) {
      #pragma unroll
      for (int c4 = 0; c4 < 4; c4++) {
        float4 v = rok ? *(const float4*)(xrow + ac0 + c4 * 4) : make_float4(0.f, 0.f, 0.f, 0.f);
        float4 sc = ((const float4*)scb)[(ac0 >> 2) + c4];
        float4 of = ((const float4*)(scb + 64))[(ac0 >> 2) + c4];
        v.x = fmaxf(v.x * sc.x + of.x, flr);
        v.y = fmaxf(v.y * sc.y + of.y, flr);
        v.z = fmaxf(v.z * sc.z + of.z, flr);
        v.w = fmaxf(v.w * sc.w + of.w, flr);
        ushort4 h4, l4;
        split4(v, h4, l4);
        *(ushort4*)&Ah[ar * 72 + ac0 + c4 * 4] = h4;
        *(ushort4*)&Al[ar * 72 + ac0 + c4 * 4] = l4;
      }
    } else {
      int kcm = kc - 1;
      const float* srcb = arow + (kcm & 3) * 64;
      int sel = kcm >> 2;
      float scale = (sel == 0) ? 1.0f : (sel == 1 ? sc_amp : sc_att);
      #pragma unroll
      for (int c4 = 0; c4 < 4; c4++) {
        float4 v = rok ? *(const float4*)(srcb + ac0 + c4 * 4) : make_float4(0.f, 0.f, 0.f, 0.f);
        v.x *= scale; v.y *= scale; v.z *= scale; v.w *= scale;
        ushort4 h4, l4;
        split4(v, h4, l4);
        *(ushort4*)&Ah[ar * 72 + ac0 + c4 * 4] = h4;
        *(ushort4*)&Al[ar * 72 + ac0 + c4 * 4] = l4;
      }
    }
    // ---- stage B chunk [64 cols][64 k]; each thread: 16 k-elems
    {
      int kbase = kc * 64;
      const ushort4* sh = (const ushort4*)(WcT_h + ar * 832 + kbase + ac0);
      const ushort4* sl = (const ushort4*)(WcT_l + ar * 832 + kbase + ac0);
      #pragma unroll
      for (int i = 0; i < 4; i++) {
        *(ushort4*)&Bh[ar * 72 + ac0 + i * 4] = sh[i];
        *(ushort4*)&Bl[ar * 72 + ac0 + i * 4] = sl[i];
      }
    }
    __syncthreads();
    #pragma unroll
    for (int ks = 0; ks < 2; ks++) {
      bf16x8 a_h[2], a_l[2], b_h[2], b_l[2];
      #pragma unroll
      for (int rt = 0; rt < 2; rt++) {
        int row = rbase + rt * 16 + l15;
        a_h[rt] = *(const bf16x8*)&Ah[row * 72 + ks * 32 + quad * 8];
        a_l[rt] = *(const bf16x8*)&Al[row * 72 + ks * 32 + quad * 8];
      }
      #pragma unroll
      for (int ct = 0; ct < 2; ct++) {
        int col = cbase + ct * 16 + l15;
        b_h[ct] = *(const bf16x8*)&Bh[col * 72 + ks * 32 + quad * 8];
        b_l[ct] = *(const bf16x8*)&Bl[col * 72 + ks * 32 + quad * 8];
      }
      #pragma unroll
      for (int rt = 0; rt < 2; rt++)
        #pragma unroll
        for (int ct = 0; ct < 2; ct++) {
          acc[rt][ct] = __builtin_amdgcn_mfma_f32_16x16x32_bf16(a_h[rt], b_h[ct], acc[rt][ct], 0, 0, 0);
          acc[rt][ct] = __builtin_amdgcn_mfma_f32_16x16x32_bf16(a_h[rt], b_l[ct], acc[rt][ct], 0, 0, 0);
          acc[rt][ct] = __builtin_amdgcn_mfma_f32_16x16x32_bf16(a_l[rt], b_h[ct], acc[rt][ct], 0, 0, 0);
        }
    }
    __syncthreads();
  }

  // ---- epilogue: bias, store y (raw, pre-BN), BN partials
  float ps[2] = {0.f, 0.f}, pq[2] = {0.f, 0.f};
  #pragma unroll
  for (int ct = 0; ct < 2; ct++) {
    int col = cbase + ct * 16 + l15;
    float bc = bcomb[col];
    #pragma unroll
    for (int rt = 0; rt < 2; rt++) {
      #pragma unroll
      for (int reg = 0; reg < 4; reg++) {
        int n = n0 + rbase + rt * 16 + quad * 4 + reg;
        float v = acc[rt][ct][reg] + bc;
        if (n < NN) {
          y[(size_t)n * FF + col] = v;
          ps[ct] += v;
          pq[ct] += v * v;
        }
      }
    }
  }
  #pragma unroll
  for (int ct = 0; ct < 2; ct++) {
    ps[ct] += __shfl_xor(ps[ct], 16);
    ps[ct] += __shfl_xor(ps[ct], 32);
    pq[ct] += __shfl_xor(pq[ct], 16);
    pq[ct] += __shfl_xor(pq[ct], 32);
  }
  if (quad == 0) {
    #pragma unroll
    for (int ct = 0; ct < 2; ct++) {
      red_s[w][ct * 16 + l15] = ps[ct];
      red_q[w][ct * 16 + l15] = pq[ct];
    }
  }
  __syncthreads();
  if (t < 64) {
    float ss, qq;
    if (t < 32) { ss = red_s[0][t] + red_s[1][t]; qq = red_q[0][t] + red_q[1][t]; }
    else        { ss = red_s[2][t - 32] + red_s[3][t - 32]; qq = red_q[2][t - 32] + red_q[3][t - 32]; }
    partials[(size_t)blockIdx.x * 128 + t] = ss;
    partials[(size_t)blockIdx.x * 128 + 64 + t] = qq;
  }
}

// ---------------------------------------------------------------- reduce BN partials -> scb (scale, offset, relu floor)
__global__ __launch_bounds__(1024) void k_bnfin(const float* __restrict__ partials,
                                                const float* __restrict__ gamma, const float* __restrict__ beta,
                                                float* __restrict__ scb) {
  __shared__ float red[1024];
  __shared__ double tot[128];
  int t = threadIdx.x;
  int c = t & 127, seg = t >> 7;
  float s = 0.f;
  for (int i = seg; i < NB64; i += 8) s += partials[(size_t)i * 128 + c];
  red[t] = s;
  __syncthreads();
  if (t < 128) {
    double d = 0.0;
    #pragma unroll
    for (int sg = 0; sg < 8; sg++) d += (double)red[sg * 128 + t];
    tot[t] = d;
  }
  __syncthreads();
  if (t < 64) {
    double mu = tot[t] / (double)NN;
    double var = tot[64 + t] / (double)NN - mu * mu;
    float sc = gamma[t] * rsqrtf((float)fmax(var, 0.0) + 1e-5f);
    scb[t] = sc;
    scb[64 + t] = beta[t] - (float)mu * sc;
  }
  if (t == 0) scb[128] = 0.0f;   // relu floor
}

// ---------------------------------------------------------------- pooling over sorted batch (BN+relu fused)
__global__ __launch_bounds__(256) void k_pool(const float* __restrict__ x, const float* __restrict__ scb,
                                              const int* __restrict__ batch,
                                              float* __restrict__ psum, float* __restrict__ cnt) {
  int lane = threadIdx.x & 63;
  int wv = threadIdx.x >> 6;
  int wglobal = blockIdx.x * 4 + wv;
  int nw = gridDim.x * 4;
  int per = (NN + nw - 1) / nw;
  int n0 = wglobal * per;
  int n1 = min(n0 + per, NN);
  if (n0 >= n1) return;
  float sc = scb[lane], of = scb[64 + lane], flr = scb[128];
  int gcur = batch[n0];
  float acc = 0.0f;
  int count = 0;
  for (int n = n0; n < n1; n++) {
    int g = batch[n];
    float v = fmaxf(x[(size_t)n * FF + lane] * sc + of, flr);
    if (g != gcur) {
      atomicAdd(&psum[gcur * FF + lane], acc);
      if (lane == 0) atomicAdd(&cnt[gcur], (float)count);
      gcur = g; acc = 0.0f; count = 0;
    }
    acc += v;
    count++;
  }
  atomicAdd(&psum[gcur * FF + lane], acc);
  if (lane == 0) atomicAdd(&cnt[gcur], (float)count);
}

// ---------------------------------------------------------------- final MLP over pooled means
__global__ void k_final(const float* __restrict__ psum, const float* __restrict__ cnt,
                        const float* __restrict__ W1, const float* __restrict__ b1,
                        const float* __restrict__ W2, const float* __restrict__ b2, float* __restrict__ out) {
  int g = threadIdx.x;
  if (g >= GG) return;
  float c = fmaxf(cnt[g], 1.0f);
  float gm[64];
  #pragma unroll
  for (int i = 0; i < 64; i++) gm[i] = psum[g * FF + i] / c;
  float o = b2[0];
  for (int h = 0; h < 40; h++) {
    float a = b1[h];
    #pragma unroll
    for (int i = 0; i < 64; i++) a += gm[i] * W1[i * 40 + h];
    o += fmaxf(a, 0.0f) * W2[h];
  }
  out[g] = o;
}

// ================================================================ launch
extern "C" void kernel_launch(void* const* d_in, const int* in_sizes, int n_in,
                              void* d_out, int out_size, void* d_ws, size_t ws_size,
                              hipStream_t stream) {
  (void)in_sizes; (void)n_in; (void)out_size; (void)ws_size;
  const float* x0    = (const float*)d_in[0];
  const float* eattr = (const float*)d_in[1];
  const float* We    = (const float*)d_in[2];
  const float* be    = (const float*)d_in[3];
  const float* Wpre  = (const float*)d_in[4];
  const float* bpre  = (const float*)d_in[5];
  const float* Wpost = (const float*)d_in[6];
  const float* bpost = (const float*)d_in[7];
  const float* Wlin  = (const float*)d_in[8];
  const float* blin  = (const float*)d_in[9];
  const float* gamma = (const float*)d_in[10];
  const float* beta  = (const float*)d_in[11];
  const float* W1    = (const float*)d_in[12];
  const float* b1    = (const float*)d_in[13];
  const float* W2    = (const float*)d_in[14];
  const float* b2    = (const float*)d_in[15];
  const int* eidx    = (const int*)d_in[16];
  const int* batch   = (const int*)d_in[17];
  float* out = (float*)d_out;

  char* w = (char*)d_ws;
  size_t off = 0;
  auto alloc = [&](size_t bytes) -> void* {
    void* p = w + off;
    off += bytes;
    off = (off + 255) & ~(size_t)255;
    return p;
  };
  int*    deg     = (int*)alloc(NN * sizeof(int));
  int*    offsets = (int*)alloc((NN + 1) * sizeof(int));
  int*    cursor  = (int*)alloc(NN * sizeof(int));
  int*    srcs    = (int*)alloc(EE * sizeof(int));
  unsigned int* PermEA = (unsigned int*)alloc((size_t)EE * 8 * sizeof(unsigned int));  // 16 bf16/edge
  int*    bsum    = (int*)alloc(NSB * sizeof(int));
  int*    bpref   = (int*)alloc(NSB * sizeof(int));
  float*  lsum    = (float*)alloc(NSB * sizeof(float));
  float*  meta    = (float*)alloc(sizeof(float));
  float*  amp     = (float*)alloc(NN * sizeof(float));
  float*  att     = (float*)alloc(NN * sizeof(float));
  float*  Mw      = (float*)alloc(EDIM * FF * sizeof(float));
  float*  bconst  = (float*)alloc(FF * sizeof(float));
  float*  bcomb   = (float*)alloc(FF * sizeof(float));
  float*  scbA    = (float*)alloc(129 * sizeof(float));    // identity (no BN, no relu)
  float*  scbB    = (float*)alloc(2 * 129 * sizeof(float)); // per-layer BN scale/offset/floor
  unsigned short* WcT_h = (unsigned short*)alloc(FF * 832 * sizeof(unsigned short));
  unsigned short* WcT_l = (unsigned short*)alloc(FF * 832 * sizeof(unsigned short));
  unsigned short* WxT_h = (unsigned short*)alloc(128 * 64 * sizeof(unsigned short));
  unsigned short* WxT_l = (unsigned short*)alloc(128 * 64 * sizeof(unsigned short));
  float*  partials = (float*)alloc((size_t)NB64 * 128 * sizeof(float));
  float*  Xd      = (float*)alloc((size_t)NN * FF * sizeof(float));
  float*  Xs      = (float*)alloc((size_t)NN * FF * sizeof(float));
  float*  aggs    = (float*)alloc((size_t)NN * 256 * sizeof(float));
  float*  ybuf    = (float*)alloc((size_t)NN * FF * sizeof(float));   // raw y; BN fused into consumers
  float*  psum    = (float*)alloc((GG * FF + GG) * sizeof(float));
  float*  cnt     = psum + GG * FF;

  hipMemsetAsync(deg, 0, NN * sizeof(int), stream);
  hipMemsetAsync(cursor, 0, NN * sizeof(int), stream);
  hipMemsetAsync(psum, 0, (GG * FF + GG) * sizeof(float), stream);

  k_deg<<<(EE + 255) / 256, 256, 0, stream>>>(eidx, deg);
  k_scanA<<<NSB, 256, 0, stream>>>(deg, offsets, bsum, lsum);
  k_scanB<<<1, 256, 0, stream>>>(bsum, lsum, bpref, meta, scbA);
  k_scanC<<<NSB, 256, 0, stream>>>(offsets, bpref, deg, meta, amp, att);
  k_scatter<<<(EE + 255) / 256, 256, 0, stream>>>(eidx, offsets, cursor, srcs, eattr, PermEA);

  const float* xin = x0;
  const float* scb_in = scbA;
  for (int l = 0; l < 2; l++) {
    k_prep2<<<245, 256, 0, stream>>>(We + l * EDIM * FF, be + l * FF, Wpre + (size_t)l * 3 * FF * FF,
                                     bpre + l * FF, Wpost + (size_t)l * 832 * FF, bpost + l * FF,
                                     Wlin + l * FF * FF, blin + l * FF,
                                     Mw, bconst, WcT_h, WcT_l, WxT_h, WxT_l, bcomb);
    k_xform<<<NB64, 256, 0, stream>>>(xin, scb_in, WxT_h, WxT_l, Xd, Xs);
    k_agg<<<(NN + 3) / 4, 256, 0, stream>>>(srcs, offsets, PermEA, Mw, bconst, Xd, Xs, aggs);
    k_post<<<NB64, 256, 0, stream>>>(xin, scb_in, aggs, amp, att, WcT_h, WcT_l, bcomb, ybuf, partials);
    k_bnfin<<<1, 1024, 0, stream>>>(partials, gamma + l * FF, beta + l * FF, scbB + l * 129);
    xin = ybuf;
    scb_in = scbB + l * 129;
  }
  k_pool<<<200, 256, 0, stream>>>(ybuf, scbB + 129, batch, psum, cnt);
  k_final<<<1, 64, 0, stream>>>(psum, cnt, W1, b1, W2, b2, out);
}

// Round 11
// 565.039 us; speedup vs baseline: 1.3146x; 1.0474x over previous
//
#include <hip/hip_runtime.h>
#include <math.h>
#include <float.h>

#define NN 50000
#define EE 800000
#define FF 64
#define EDIM 16
#define GG 64
#define NB64 782   // ceil(NN/64)
#define NSB 196    // ceil(NN/256) scan blocks

typedef short bf16x8 __attribute__((ext_vector_type(8)));
typedef float f32x4 __attribute__((ext_vector_type(4)));

__device__ inline unsigned short bf_rne(float v) {
  unsigned int u = __float_as_uint(v);
  unsigned int r = (u + 0x7FFFu + ((u >> 16) & 1u)) >> 16;
  return (unsigned short)r;
}
__device__ inline float bf_up(unsigned short h) {
  return __uint_as_float(((unsigned int)h) << 16);
}
__device__ inline void split4(float4 v, ushort4& h, ushort4& l) {
  h.x = bf_rne(v.x); h.y = bf_rne(v.y); h.z = bf_rne(v.z); h.w = bf_rne(v.w);
  l.x = bf_rne(v.x - bf_up(h.x));
  l.y = bf_rne(v.y - bf_up(h.y));
  l.z = bf_rne(v.z - bf_up(h.z));
  l.w = bf_rne(v.w - bf_up(h.w));
}
__device__ inline float blo(unsigned int u) { return __uint_as_float(u << 16); }
__device__ inline float bhi(unsigned int u) { return __uint_as_float(u & 0xFFFF0000u); }

// ---------------------------------------------------------------- degree
__global__ void k_deg(const int* __restrict__ eidx, int* __restrict__ deg) {
  int e = blockIdx.x * 256 + threadIdx.x;
  if (e < EE) atomicAdd(&deg[eidx[EE + e]], 1);
}

// ---------------------------------------------------------------- scan pass A
__global__ __launch_bounds__(256) void k_scanA(const int* __restrict__ deg, int* __restrict__ offsets,
                                               int* __restrict__ bsum, float* __restrict__ lsum) {
  __shared__ int ws[4];
  __shared__ float lw[4];
  int t = threadIdx.x;
  int lane = t & 63;
  int wv = t >> 6;
  int i = blockIdx.x * 256 + t;
  int v = (i < NN) ? deg[i] : 0;
  float lg = (i < NN) ? logf((float)v + 1.0f) : 0.0f;
  int x = v;
  #pragma unroll
  for (int o = 1; o < 64; o <<= 1) {
    int y = __shfl_up(x, o);
    if (lane >= o) x += y;
  }
  #pragma unroll
  for (int o = 1; o < 64; o <<= 1) lg += __shfl_xor(lg, o);
  if (lane == 63) ws[wv] = x;
  if (lane == 0) lw[wv] = lg;
  __syncthreads();
  int pre = 0;
  for (int k = 0; k < wv; k++) pre += ws[k];
  if (i < NN) offsets[i] = pre + x - v;
  if (t == 0) {
    bsum[blockIdx.x] = ws[0] + ws[1] + ws[2] + ws[3];
    lsum[blockIdx.x] = lw[0] + lw[1] + lw[2] + lw[3];
  }
}

// ---------------------------------------------------------------- scan pass B
__global__ __launch_bounds__(256) void k_scanB(const int* __restrict__ bsum, const float* __restrict__ lsum,
                                               int* __restrict__ bpref, float* __restrict__ meta,
                                               float* __restrict__ scbA) {
  __shared__ int ws[4];
  __shared__ float lw[4];
  int t = threadIdx.x;
  int lane = t & 63;
  int wv = t >> 6;
  int v = (t < NSB) ? bsum[t] : 0;
  float lg = (t < NSB) ? lsum[t] : 0.0f;
  int x = v;
  #pragma unroll
  for (int o = 1; o < 64; o <<= 1) {
    int y = __shfl_up(x, o);
    if (lane >= o) x += y;
  }
  #pragma unroll
  for (int o = 1; o < 64; o <<= 1) lg += __shfl_xor(lg, o);
  if (lane == 63) ws[wv] = x;
  if (lane == 0) lw[wv] = lg;
  __syncthreads();
  int pre = 0;
  for (int k = 0; k < wv; k++) pre += ws[k];
  if (t < NSB) bpref[t] = pre + x - v;
  if (t == 0) meta[0] = (lw[0] + lw[1] + lw[2] + lw[3]) / (float)NN;
  if (t < 64) { scbA[t] = 1.0f; scbA[64 + t] = 0.0f; }
  if (t == 0) scbA[128] = -FLT_MAX;
}

// ---------------------------------------------------------------- scan pass C
__global__ __launch_bounds__(256) void k_scanC(int* __restrict__ offsets, const int* __restrict__ bpref,
                                               const int* __restrict__ deg, const float* __restrict__ meta,
                                               float* __restrict__ amp, float* __restrict__ att) {
  int i = blockIdx.x * 256 + threadIdx.x;
  if (i < NN) {
    offsets[i] += bpref[blockIdx.x];
    float d = (float)deg[i];
    float avg = meta[0];
    float logd = logf(fmaxf(d, 1.0f) + 1.0f);
    amp[i] = logd / avg;
    att[i] = avg / logd;
  }
  if (i == 0) offsets[NN] = EE;
}

// ---------------------------------------------------------------- scatter + permute eattr (bf16)
__global__ void k_scatter(const int* __restrict__ eidx, const int* __restrict__ offsets,
                          int* __restrict__ cursor, int* __restrict__ srcs,
                          const float* __restrict__ eattr, unsigned int* __restrict__ PermEA) {
  int e = blockIdx.x * 256 + threadIdx.x;
  if (e < EE) {
    int s = eidx[e];
    int d = eidx[EE + e];
    int pos = offsets[d] + atomicAdd(&cursor[d], 1);
    srcs[pos] = s;
    const float4* ep = (const float4*)(eattr + (size_t)e * EDIM);
    float4 q0 = ep[0], q1 = ep[1], q2 = ep[2], q3 = ep[3];
    uint4 pa, pb;
    pa.x = (unsigned)bf_rne(q0.x) | ((unsigned)bf_rne(q0.y) << 16);
    pa.y = (unsigned)bf_rne(q0.z) | ((unsigned)bf_rne(q0.w) << 16);
    pa.z = (unsigned)bf_rne(q1.x) | ((unsigned)bf_rne(q1.y) << 16);
    pa.w = (unsigned)bf_rne(q1.z) | ((unsigned)bf_rne(q1.w) << 16);
    pb.x = (unsigned)bf_rne(q2.x) | ((unsigned)bf_rne(q2.y) << 16);
    pb.y = (unsigned)bf_rne(q2.z) | ((unsigned)bf_rne(q2.w) << 16);
    pb.z = (unsigned)bf_rne(q3.x) | ((unsigned)bf_rne(q3.y) << 16);
    pb.w = (unsigned)bf_rne(q3.z) | ((unsigned)bf_rne(q3.w) << 16);
    ((uint4*)PermEA)[(size_t)pos * 2] = pa;
    ((uint4*)PermEA)[(size_t)pos * 2 + 1] = pb;
  }
}

// ---------------------------------------------------------------- per-layer prep
__global__ __launch_bounds__(256) void k_prep2(const float* __restrict__ We, const float* __restrict__ be,
                                               const float* __restrict__ Wpre, const float* __restrict__ bpre,
                                               const float* __restrict__ Wpost, const float* __restrict__ bpost,
                                               const float* __restrict__ Wlin, const float* __restrict__ blin,
                                               float* __restrict__ Mw, float* __restrict__ bconst,
                                               unsigned short* __restrict__ WcT_h, unsigned short* __restrict__ WcT_l,
                                               unsigned short* __restrict__ WxT_h, unsigned short* __restrict__ WxT_l,
                                               float* __restrict__ bcomb) {
  int id = blockIdx.x * 256 + threadIdx.x;
  if (id < 53248) {                      // WcombT
    int k = id >> 6, f = id & 63;
    float a = 0.0f;
    for (int j = 0; j < FF; j++) a += Wpost[(size_t)k * FF + j] * Wlin[j * FF + f];
    unsigned short h = bf_rne(a);
    WcT_h[f * 832 + k] = h;
    WcT_l[f * 832 + k] = bf_rne(a - bf_up(h));
  } else if (id < 61440) {               // WxT
    int lid = id - 53248;
    int j = lid >> 6, k = lid & 63;
    float v = (j < 64) ? Wpre[k * FF + j] : Wpre[(64 + k) * FF + (j - 64)];
    unsigned short h = bf_rne(v);
    WxT_h[j * 64 + k] = h;
    WxT_l[j * 64 + k] = bf_rne(v - bf_up(h));
  } else if (id < 62464) {               // Mw
    int lid = id - 61440;
    int k = lid >> 6, f = lid & 63;
    float a = 0.0f;
    for (int j = 0; j < FF; j++) a += We[k * FF + j] * Wpre[(128 + j) * FF + f];
    Mw[k * FF + f] = a;
  } else {                               // biases
    int f = threadIdx.x;
    if (blockIdx.x == 244 && f < 64) {
      float b = bpre[f];
      for (int j = 0; j < FF; j++) b += be[j] * Wpre[(128 + j) * FF + f];
      bconst[f] = b;
      float c = blin[f];
      for (int j = 0; j < FF; j++) c += bpost[j] * Wlin[j * FF + f];
      bcomb[f] = c;
    }
  }
}

// ---------------------------------------------------------------- [Xd|Xs] = bn(x) @ Wx via bf16x3 MFMA; Xs stored bf16
__global__ __launch_bounds__(256) void k_xform(const float* __restrict__ x, const float* __restrict__ scb,
                                               const unsigned short* __restrict__ WxT_h,
                                               const unsigned short* __restrict__ WxT_l,
                                               float* __restrict__ Xd, unsigned short* __restrict__ Xs) {
  __shared__ unsigned short Ah[64 * 72], Al[64 * 72];
  __shared__ unsigned short Bh[128 * 72], Bl[128 * 72];
  int t = threadIdx.x;
  int n0 = blockIdx.x * 64;
  {
    int j = t >> 1, half = t & 1;
    const ushort4* srch = (const ushort4*)(WxT_h + j * 64 + half * 32);
    const ushort4* srcl = (const ushort4*)(WxT_l + j * 64 + half * 32);
    #pragma unroll
    for (int i = 0; i < 8; i++) {
      *(ushort4*)&Bh[j * 72 + half * 32 + i * 4] = srch[i];
      *(ushort4*)&Bl[j * 72 + half * 32 + i * 4] = srcl[i];
    }
  }
  {
    int r = t >> 2, c0 = (t & 3) * 16;
    int n = n0 + r;
    bool rok = n < NN;
    const float4* src = (const float4*)(x + (size_t)n * FF + c0);
    float flr = scb[128];
    #pragma unroll
    for (int c4 = 0; c4 < 4; c4++) {
      float4 v = rok ? src[c4] : make_float4(0.f, 0.f, 0.f, 0.f);
      float4 sc = ((const float4*)scb)[(c0 >> 2) + c4];
      float4 of = ((const float4*)(scb + 64))[(c0 >> 2) + c4];
      v.x = fmaxf(v.x * sc.x + of.x, flr);
      v.y = fmaxf(v.y * sc.y + of.y, flr);
      v.z = fmaxf(v.z * sc.z + of.z, flr);
      v.w = fmaxf(v.w * sc.w + of.w, flr);
      ushort4 h4, l4;
      split4(v, h4, l4);
      *(ushort4*)&Ah[r * 72 + c0 + c4 * 4] = h4;
      *(ushort4*)&Al[r * 72 + c0 + c4 * 4] = l4;
    }
  }
  __syncthreads();
  int lane = t & 63;
  int l15 = lane & 15;
  int quad = lane >> 4;
  int w = __builtin_amdgcn_readfirstlane(t >> 6);
  int rbase = (w & 1) * 32;
  int cbase = (w >> 1) * 64;
  f32x4 acc[2][4];
  #pragma unroll
  for (int rt = 0; rt < 2; rt++)
    #pragma unroll
    for (int ct = 0; ct < 4; ct++) acc[rt][ct] = (f32x4){0.f, 0.f, 0.f, 0.f};

  #pragma unroll
  for (int ks = 0; ks < 2; ks++) {
    bf16x8 a_h[2], a_l[2];
    #pragma unroll
    for (int rt = 0; rt < 2; rt++) {
      int row = rbase + rt * 16 + l15;
      a_h[rt] = *(const bf16x8*)&Ah[row * 72 + ks * 32 + quad * 8];
      a_l[rt] = *(const bf16x8*)&Al[row * 72 + ks * 32 + quad * 8];
    }
    #pragma unroll
    for (int ct = 0; ct < 4; ct++) {
      int col = cbase + ct * 16 + l15;
      bf16x8 b_h = *(const bf16x8*)&Bh[col * 72 + ks * 32 + quad * 8];
      bf16x8 b_l = *(const bf16x8*)&Bl[col * 72 + ks * 32 + quad * 8];
      #pragma unroll
      for (int rt = 0; rt < 2; rt++) {
        acc[rt][ct] = __builtin_amdgcn_mfma_f32_16x16x32_bf16(a_h[rt], b_h, acc[rt][ct], 0, 0, 0);
        acc[rt][ct] = __builtin_amdgcn_mfma_f32_16x16x32_bf16(a_h[rt], b_l, acc[rt][ct], 0, 0, 0);
        acc[rt][ct] = __builtin_amdgcn_mfma_f32_16x16x32_bf16(a_l[rt], b_h, acc[rt][ct], 0, 0, 0);
      }
    }
  }
  // store: cols 0..63 -> Xd (f32), 64..127 -> Xs (bf16)
  #pragma unroll
  for (int rt = 0; rt < 2; rt++) {
    #pragma unroll
    for (int ct = 0; ct < 4; ct++) {
      int col = cbase + ct * 16 + l15;
      #pragma unroll
      for (int reg = 0; reg < 4; reg++) {
        int n = n0 + rbase + rt * 16 + quad * 4 + reg;
        if (n < NN) {
          float v = acc[rt][ct][reg];
          if (col < 64) Xd[(size_t)n * FF + col] = v;
          else          Xs[(size_t)n * FF + (col - 64)] = bf_rne(v);
        }
      }
    }
  }
}

// ---------------------------------------------------------------- per-node CSR aggregation (bf16 Xs + sequential bf16 PermEA; bf16 aggs out)
__global__ __launch_bounds__(256) void k_agg(const int* __restrict__ srcs, const int* __restrict__ offsets,
                                             const unsigned int* __restrict__ PermEA,
                                             const float* __restrict__ Mw, const float* __restrict__ bconst,
                                             const float* __restrict__ Xd, const unsigned short* __restrict__ Xs,
                                             unsigned short* __restrict__ aggs) {
  int wid = __builtin_amdgcn_readfirstlane(threadIdx.x >> 6);
  int lane = threadIdx.x & 63;
  int n = blockIdx.x * 4 + wid;
  if (n >= NN) return;
  float mw[16];
  #pragma unroll
  for (int k = 0; k < 16; k++) mw[k] = Mw[k * FF + lane];
  float base_h = Xd[(size_t)n * FF + lane] + bconst[lane];
  int o0 = offsets[n], o1 = offsets[n + 1];
  float s = 0.f, sq = 0.f, mn = FLT_MAX, mx = -FLT_MAX;

  for (int base = o0; base < o1; base += 64) {
    int m = min(64, o1 - base);
    int sv = 0;
    if (base + lane < o1) sv = srcs[base + lane];
    for (int j = 0; j < m; j++) {
      int src = __shfl(sv, j);
      float xs = bf_up(Xs[(size_t)src * FF + lane]);
      const uint4* q = (const uint4*)PermEA + (size_t)(base + j) * 2;
      uint4 qa = q[0], qb = q[1];
      float et = blo(qa.x) * mw[0]  + bhi(qa.x) * mw[1]
               + blo(qa.y) * mw[2]  + bhi(qa.y) * mw[3]
               + blo(qa.z) * mw[4]  + bhi(qa.z) * mw[5]
               + blo(qa.w) * mw[6]  + bhi(qa.w) * mw[7]
               + blo(qb.x) * mw[8]  + bhi(qb.x) * mw[9]
               + blo(qb.y) * mw[10] + bhi(qb.y) * mw[11]
               + blo(qb.z) * mw[12] + bhi(qb.z) * mw[13]
               + blo(qb.w) * mw[14] + bhi(qb.w) * mw[15];
      float h = base_h + xs + et;
      s += h;
      sq += h * h;
      mn = fminf(mn, h);
      mx = fmaxf(mx, h);
    }
  }
  float d = (float)(o1 - o0);
  float dc = fmaxf(d, 1.0f);
  float mean = s / dc;
  float msq = sq / dc;
  float sd = sqrtf(fmaxf(msq - mean * mean, 0.0f) + 1e-5f);
  bool has = d > 0.0f;
  float vmn = has ? mn : 0.0f;
  float vmx = has ? mx : 0.0f;
  size_t b = (size_t)n * 256;
  aggs[b + lane] = bf_rne(mean);
  aggs[b + 64 + lane] = bf_rne(vmn);
  aggs[b + 128 + lane] = bf_rne(vmx);
  aggs[b + 192 + lane] = bf_rne(sd);
}

// ---------------------------------------------------------------- y = [bn(x),scaled aggs] @ Wcomb + bcomb (bf16 MFMA) + BN partials
// x chunk: bf16x3 (full precision); agg chunks: bf16 source -> 2 MFMAs (a_h only)
__global__ __launch_bounds__(256) void k_post(const float* __restrict__ x, const float* __restrict__ scb,
                                              const unsigned short* __restrict__ aggs,
                                              const float* __restrict__ amp, const float* __restrict__ att,
                                              const unsigned short* __restrict__ WcT_h,
                                              const unsigned short* __restrict__ WcT_l,
                                              const float* __restrict__ bcomb,
                                              float* __restrict__ y, float* __restrict__ partials) {
  __shared__ unsigned short Ah[64 * 72], Al[64 * 72];
  __shared__ unsigned short Bh[64 * 72], Bl[64 * 72];
  __shared__ float red_s[4][32], red_q[4][32];
  int t = threadIdx.x;
  int n0 = blockIdx.x * 64;
  int lane = t & 63;
  int l15 = lane & 15;
  int quad = lane >> 4;
  int w = __builtin_amdgcn_readfirstlane(t >> 6);
  int rbase = (w & 1) * 32;
  int cbase = (w >> 1) * 32;

  int ar = t >> 2;
  int ac0 = (t & 3) * 16;
  int an = n0 + ar;
  bool rok = an < NN;
  float sc_amp = rok ? amp[an] : 0.f;
  float sc_att = rok ? att[an] : 0.f;
  const float* xrow = x + (size_t)an * FF;
  const unsigned short* arow = aggs + (size_t)an * 256;
  float flr = scb[128];

  f32x4 acc[2][2];
  #pragma unroll
  for (int rt = 0; rt < 2; rt++)
    #pragma unroll
    for (int ct = 0; ct < 2; ct++) acc[rt][ct] = (f32x4){0.f, 0.f, 0.f, 0.f};

  for (int kc = 0; kc < 13; kc++) {
    if (kc == 0) {
      // bn(x) -> hi/lo bf16
      #pragma unroll
      for (int c4 = 0; c4 < 4; c4++) {
        float4 v = rok ? *(const float4*)(xrow + ac0 + c4 * 4) : make_float4(0.f, 0.f, 0.f, 0.f);
        float4 sc = ((const float4*)scb)[(ac0 >> 2) + c4];
        float4 of = ((const float4*)(scb + 64))[(ac0 >> 2) + c4];
        v.x = fmaxf(v.x * sc.x + of.x, flr);
        v.y = fmaxf(v.y * sc.y + of.y, flr);
        v.z = fmaxf(v.z * sc.z + of.z, flr);
        v.w = fmaxf(v.w * sc.w + of.w, flr);
        ushort4 h4, l4;
        split4(v, h4, l4);
        *(ushort4*)&Ah[ar * 72 + ac0 + c4 * 4] = h4;
        *(ushort4*)&Al[ar * 72 + ac0 + c4 * 4] = l4;
      }
    } else {
      int kcm = kc - 1;
      const unsigned short* srcb = arow + (kcm & 3) * 64;
      int sel = kcm >> 2;
      float scale = (sel == 0) ? 1.0f : (sel == 1 ? sc_amp : sc_att);
      #pragma unroll
      for (int c4 = 0; c4 < 4; c4++) {
        ushort4 u = rok ? *(const ushort4*)(srcb + ac0 + c4 * 4) : make_ushort4(0, 0, 0, 0);
        ushort4 h4;
        h4.x = bf_rne(bf_up(u.x) * scale);
        h4.y = bf_rne(bf_up(u.y) * scale);
        h4.z = bf_rne(bf_up(u.z) * scale);
        h4.w = bf_rne(bf_up(u.w) * scale);
        *(ushort4*)&Ah[ar * 72 + ac0 + c4 * 4] = h4;
      }
    }
    // stage B chunk
    {
      int kbase = kc * 64;
      const ushort4* sh = (const ushort4*)(WcT_h + ar * 832 + kbase + ac0);
      const ushort4* sl = (const ushort4*)(WcT_l + ar * 832 + kbase + ac0);
      #pragma unroll
      for (int i = 0; i < 4; i++) {
        *(ushort4*)&Bh[ar * 72 + ac0 + i * 4] = sh[i];
        *(ushort4*)&Bl[ar * 72 + ac0 + i * 4] = sl[i];
      }
    }
    __syncthreads();
    bool full = (kc == 0);
    #pragma unroll
    for (int ks = 0; ks < 2; ks++) {
      bf16x8 a_h[2], a_l[2], b_h[2], b_l[2];
      #pragma unroll
      for (int rt = 0; rt < 2; rt++) {
        int row = rbase + rt * 16 + l15;
        a_h[rt] = *(const bf16x8*)&Ah[row * 72 + ks * 32 + quad * 8];
        if (full) a_l[rt] = *(const bf16x8*)&Al[row * 72 + ks * 32 + quad * 8];
      }
      #pragma unroll
      for (int ct = 0; ct < 2; ct++) {
        int col = cbase + ct * 16 + l15;
        b_h[ct] = *(const bf16x8*)&Bh[col * 72 + ks * 32 + quad * 8];
        b_l[ct] = *(const bf16x8*)&Bl[col * 72 + ks * 32 + quad * 8];
      }
      #pragma unroll
      for (int rt = 0; rt < 2; rt++)
        #pragma unroll
        for (int ct = 0; ct < 2; ct++) {
          acc[rt][ct] = __builtin_amdgcn_mfma_f32_16x16x32_bf16(a_h[rt], b_h[ct], acc[rt][ct], 0, 0, 0);
          acc[rt][ct] = __builtin_amdgcn_mfma_f32_16x16x32_bf16(a_h[rt], b_l[ct], acc[rt][ct], 0, 0, 0);
          if (full)
            acc[rt][ct] = __builtin_amdgcn_mfma_f32_16x16x32_bf16(a_l[rt], b_h[ct], acc[rt][ct], 0, 0, 0);
        }
    }
    __syncthreads();
  }

  // epilogue: bias, store raw y, BN partials
  float ps[2] = {0.f, 0.f}, pq[2] = {0.f, 0.f};
  #pragma unroll
  for (int ct = 0; ct < 2; ct++) {
    int col = cbase + ct * 16 + l15;
    float bc = bcomb[col];
    #pragma unroll
    for (int rt = 0; rt < 2; rt++) {
      #pragma unroll
      for (int reg = 0; reg < 4; reg++) {
        int n = n0 + rbase + rt * 16 + quad * 4 + reg;
        float v = acc[rt][ct][reg] + bc;
        if (n < NN) {
          y[(size_t)n * FF + col] = v;
          ps[ct] += v;
          pq[ct] += v * v;
        }
      }
    }
  }
  #pragma unroll
  for (int ct = 0; ct < 2; ct++) {
    ps[ct] += __shfl_xor(ps[ct], 16);
    ps[ct] += __shfl_xor(ps[ct], 32);
    pq[ct] += __shfl_xor(pq[ct], 16);
    pq[ct] += __shfl_xor(pq[ct], 32);
  }
  if (quad == 0) {
    #pragma unroll
    for (int ct = 0; ct < 2; ct++) {
      red_s[w][ct * 16 + l15] = ps[ct];
      red_q[w][ct * 16 + l15] = pq[ct];
    }
  }
  __syncthreads();
  if (t < 64) {
    float ss, qq;
    if (t < 32) { ss = red_s[0][t] + red_s[1][t]; qq = red_q[0][t] + red_q[1][t]; }
    else        { ss = red_s[2][t - 32] + red_s[3][t - 32]; qq = red_q[2][t - 32] + red_q[3][t - 32]; }
    partials[(size_t)blockIdx.x * 128 + t] = ss;
    partials[(size_t)blockIdx.x * 128 + 64 + t] = qq;
  }
}

// ---------------------------------------------------------------- reduce BN partials -> scb
__global__ __launch_bounds__(1024) void k_bnfin(const float* __restrict__ partials,
                                                const float* __restrict__ gamma, const float* __restrict__ beta,
                                                float* __restrict__ scb) {
  __shared__ float red[1024];
  __shared__ double tot[128];
  int t = threadIdx.x;
  int c = t & 127, seg = t >> 7;
  float s = 0.f;
  for (int i = seg; i < NB64; i += 8) s += partials[(size_t)i * 128 + c];
  red[t] = s;
  __syncthreads();
  if (t < 128) {
    double d = 0.0;
    #pragma unroll
    for (int sg = 0; sg < 8; sg++) d += (double)red[sg * 128 + t];
    tot[t] = d;
  }
  __syncthreads();
  if (t < 64) {
    double mu = tot[t] / (double)NN;
    double var = tot[64 + t] / (double)NN - mu * mu;
    float sc = gamma[t] * rsqrtf((float)fmax(var, 0.0) + 1e-5f);
    scb[t] = sc;
    scb[64 + t] = beta[t] - (float)mu * sc;
  }
  if (t == 0) scb[128] = 0.0f;
}

// ---------------------------------------------------------------- pooling (BN+relu fused)
__global__ __launch_bounds__(256) void k_pool(const float* __restrict__ x, const float* __restrict__ scb,
                                              const int* __restrict__ batch,
                                              float* __restrict__ psum, float* __restrict__ cnt) {
  int lane = threadIdx.x & 63;
  int wv = threadIdx.x >> 6;
  int wglobal = blockIdx.x * 4 + wv;
  int nw = gridDim.x * 4;
  int per = (NN + nw - 1) / nw;
  int n0 = wglobal * per;
  int n1 = min(n0 + per, NN);
  if (n0 >= n1) return;
  float sc = scb[lane], of = scb[64 + lane], flr = scb[128];
  int gcur = batch[n0];
  float acc = 0.0f;
  int count = 0;
  for (int n = n0; n < n1; n++) {
    int g = batch[n];
    float v = fmaxf(x[(size_t)n * FF + lane] * sc + of, flr);
    if (g != gcur) {
      atomicAdd(&psum[gcur * FF + lane], acc);
      if (lane == 0) atomicAdd(&cnt[gcur], (float)count);
      gcur = g; acc = 0.0f; count = 0;
    }
    acc += v;
    count++;
  }
  atomicAdd(&psum[gcur * FF + lane], acc);
  if (lane == 0) atomicAdd(&cnt[gcur], (float)count);
}

// ---------------------------------------------------------------- final MLP
__global__ void k_final(const float* __restrict__ psum, const float* __restrict__ cnt,
                        const float* __restrict__ W1, const float* __restrict__ b1,
                        const float* __restrict__ W2, const float* __restrict__ b2, float* __restrict__ out) {
  int g = threadIdx.x;
  if (g >= GG) return;
  float c = fmaxf(cnt[g], 1.0f);
  float gm[64];
  #pragma unroll
  for (int i = 0; i < 64; i++) gm[i] = psum[g * FF + i] / c;
  float o = b2[0];
  for (int h = 0; h < 40; h++) {
    float a = b1[h];
    #pragma unroll
    for (int i = 0; i < 64; i++) a += gm[i] * W1[i * 40 + h];
    o += fmaxf(a, 0.0f) * W2[h];
  }
  out[g] = o;
}

// ================================================================ launch
extern "C" void kernel_launch(void* const* d_in, const int* in_sizes, int n_in,
                              void* d_out, int out_size, void* d_ws, size_t ws_size,
                              hipStream_t stream) {
  (void)in_sizes; (void)n_in; (void)out_size; (void)ws_size;
  const float* x0    = (const float*)d_in[0];
  const float* eattr = (const float*)d_in[1];
  const float* We    = (const float*)d_in[2];
  const float* be    = (const float*)d_in[3];
  const float* Wpre  = (const float*)d_in[4];
  const float* bpre  = (const float*)d_in[5];
  const float* Wpost = (const float*)d_in[6];
  const float* bpost = (const float*)d_in[7];
  const float* Wlin  = (const float*)d_in[8];
  const float* blin  = (const float*)d_in[9];
  const float* gamma = (const float*)d_in[10];
  const float* beta  = (const float*)d_in[11];
  const float* W1    = (const float*)d_in[12];
  const float* b1    = (const float*)d_in[13];
  const float* W2    = (const float*)d_in[14];
  const float* b2    = (const float*)d_in[15];
  const int* eidx    = (const int*)d_in[16];
  const int* batch   = (const int*)d_in[17];
  float* out = (float*)d_out;

  char* w = (char*)d_ws;
  size_t off = 0;
  auto alloc = [&](size_t bytes) -> void* {
    void* p = w + off;
    off += bytes;
    off = (off + 255) & ~(size_t)255;
    return p;
  };
  int*    deg     = (int*)alloc(NN * sizeof(int));
  int*    offsets = (int*)alloc((NN + 1) * sizeof(int));
  int*    cursor  = (int*)alloc(NN * sizeof(int));
  int*    srcs    = (int*)alloc(EE * sizeof(int));
  unsigned int* PermEA = (unsigned int*)alloc((size_t)EE * 8 * sizeof(unsigned int));
  int*    bsum    = (int*)alloc(NSB * sizeof(int));
  int*    bpref   = (int*)alloc(NSB * sizeof(int));
  float*  lsum    = (float*)alloc(NSB * sizeof(float));
  float*  meta    = (float*)alloc(sizeof(float));
  float*  amp     = (float*)alloc(NN * sizeof(float));
  float*  att     = (float*)alloc(NN * sizeof(float));
  float*  Mw      = (float*)alloc(EDIM * FF * sizeof(float));
  float*  bconst  = (float*)alloc(FF * sizeof(float));
  float*  bcomb   = (float*)alloc(FF * sizeof(float));
  float*  scbA    = (float*)alloc(129 * sizeof(float));
  float*  scbB    = (float*)alloc(2 * 129 * sizeof(float));
  unsigned short* WcT_h = (unsigned short*)alloc(FF * 832 * sizeof(unsigned short));
  unsigned short* WcT_l = (unsigned short*)alloc(FF * 832 * sizeof(unsigned short));
  unsigned short* WxT_h = (unsigned short*)alloc(128 * 64 * sizeof(unsigned short));
  unsigned short* WxT_l = (unsigned short*)alloc(128 * 64 * sizeof(unsigned short));
  float*  partials = (float*)alloc((size_t)NB64 * 128 * sizeof(float));
  float*  Xd      = (float*)alloc((size_t)NN * FF * sizeof(float));
  unsigned short* Xs = (unsigned short*)alloc((size_t)NN * FF * sizeof(unsigned short));
  unsigned short* aggs = (unsigned short*)alloc((size_t)NN * 256 * sizeof(unsigned short));
  float*  ybuf    = (float*)alloc((size_t)NN * FF * sizeof(float));
  float*  psum    = (float*)alloc((GG * FF + GG) * sizeof(float));
  float*  cnt     = psum + GG * FF;

  hipMemsetAsync(deg, 0, NN * sizeof(int), stream);
  hipMemsetAsync(cursor, 0, NN * sizeof(int), stream);
  hipMemsetAsync(psum, 0, (GG * FF + GG) * sizeof(float), stream);

  k_deg<<<(EE + 255) / 256, 256, 0, stream>>>(eidx, deg);
  k_scanA<<<NSB, 256, 0, stream>>>(deg, offsets, bsum, lsum);
  k_scanB<<<1, 256, 0, stream>>>(bsum, lsum, bpref, meta, scbA);
  k_scanC<<<NSB, 256, 0, stream>>>(offsets, bpref, deg, meta, amp, att);
  k_scatter<<<(EE + 255) / 256, 256, 0, stream>>>(eidx, offsets, cursor, srcs, eattr, PermEA);

  const float* xin = x0;
  const float* scb_in = scbA;
  for (int l = 0; l < 2; l++) {
    k_prep2<<<245, 256, 0, stream>>>(We + l * EDIM * FF, be + l * FF, Wpre + (size_t)l * 3 * FF * FF,
                                     bpre + l * FF, Wpost + (size_t)l * 832 * FF, bpost + l * FF,
                                     Wlin + l * FF * FF, blin + l * FF,
                                     Mw, bconst, WcT_h, WcT_l, WxT_h, WxT_l, bcomb);
    k_xform<<<NB64, 256, 0, stream>>>(xin, scb_in, WxT_h, WxT_l, Xd, Xs);
    k_agg<<<(NN + 3) / 4, 256, 0, stream>>>(srcs, offsets, PermEA, Mw, bconst, Xd, Xs, aggs);
    k_post<<<NB64, 256, 0, stream>>>(xin, scb_in, aggs, amp, att, WcT_h, WcT_l, bcomb, ybuf, partials);
    k_bnfin<<<1, 1024, 0, stream>>>(partials, gamma + l * FF, beta + l * FF, scbB + l * 129);
    xin = ybuf;
    scb_in = scbB + l * 129;
  }
  k_pool<<<200, 256, 0, stream>>>(ybuf, scbB + 129, batch, psum, cnt);
  k_final<<<1, 64, 0, stream>>>(psum, cnt, W1, b1, W2, b2, out);
}